// Round 9
// baseline (2723.597 us; speedup 1.0000x reference)
//
#include <hip/hip_runtime.h>
#include <hip/hip_fp16.h>

// PolyConv via CSR-gather. Build = LDS counting sort (no global atomics),
// packed 4B edge records {src:17 | q15(mask):15}, fp16 gather mirror
// pre-scaled by dinv[src] (ping-pong m0/m1), in-place fp32 feature chain.
// Aggregate: 2 nodes per wave (32 lanes each).
// feat [N,32] f32, src [E] i32, dst [E] i32, mask [E] f32 -> h [N,32] f32.

#define FDIM 32
#define DLO_BITS 8
#define BKT_NODES 256          // nodes per bucket = 1<<DLO_BITS
#define NBLK 512               // partition blocks for P1/P3
#define MAXBKT 512             // supports N <= 131072 (src fits 17 bits)

// ---------------- build ----------------

// P1: per-block bucket histogram. cntT[g*NBLK + b].
__global__ __launch_bounds__(256) void p1_kernel(const int* __restrict__ dst,
                                                 int* __restrict__ cntT,
                                                 int nbkt, int S, int E) {
    __shared__ int lh[MAXBKT];
    int b = blockIdx.x;
    for (int t = threadIdx.x; t < MAXBKT; t += 256) lh[t] = 0;
    __syncthreads();
    int e0 = b * S;
    int e1 = e0 + S < E ? e0 + S : E;
    for (int e = e0 + threadIdx.x; e < e1; e += 256)
        atomicAdd(&lh[dst[e] >> DLO_BITS], 1);
    __syncthreads();
    for (int t = threadIdx.x; t < nbkt; t += 256) cntT[t * NBLK + b] = lh[t];
}

// generic exclusive block scan (256/block) of cntT -> obase, block sums -> bsums
__global__ void scanA_kernel(const int* __restrict__ cntT, int* __restrict__ obase,
                             int* __restrict__ bsums, int M2) {
    int tid = threadIdx.x;
    int gid = blockIdx.x * 256 + tid;
    int v = (gid < M2) ? cntT[gid] : 0;
    int lane = tid & 63, wv = tid >> 6;
    int x = v;
#pragma unroll
    for (int o = 1; o < 64; o <<= 1) {
        int y = __shfl_up(x, o);
        if (lane >= o) x += y;
    }
    __shared__ int ws[4];
    if (lane == 63) ws[wv] = x;
    __syncthreads();
    int add = 0;
    for (int i = 0; i < wv; ++i) add += ws[i];
    x += add;
    if (gid < M2) obase[gid] = x - v;
    if (tid == 255) bsums[blockIdx.x] = x;
}

// single block (512 threads), scans bsums in place (exclusive), loops if nb>512
__global__ void scan2_kernel(int* __restrict__ bsums, int nb) {
    __shared__ int ws[8];
    __shared__ int carry;
    if (threadIdx.x == 0) carry = 0;
    __syncthreads();
    for (int base = 0; base < nb; base += 512) {
        int i = base + threadIdx.x;
        int v = (i < nb) ? bsums[i] : 0;
        int lane = threadIdx.x & 63, wv = threadIdx.x >> 6;
        int x = v;
#pragma unroll
        for (int o = 1; o < 64; o <<= 1) {
            int y = __shfl_up(x, o);
            if (lane >= o) x += y;
        }
        if (lane == 63) ws[wv] = x;
        __syncthreads();
        int add = 0;
        for (int j = 0; j < wv; ++j) add += ws[j];
        x += add;
        int c = carry;
        if (i < nb) bsums[i] = x - v + c;
        __syncthreads();
        if (threadIdx.x == 511) carry = c + x;
        __syncthreads();
    }
}

__global__ void scanC_kernel(int* __restrict__ obase, const int* __restrict__ bsums, int M2) {
    int gid = blockIdx.x * 256 + threadIdx.x;
    if (gid < M2) obase[gid] += bsums[blockIdx.x];
}

// P3: bucket-partition scatter. Same partition as P1; LDS rank within (block,bucket).
// esp[pos] = { src | (dlo<<17), bits(mask) }.
__global__ __launch_bounds__(256) void p3_kernel(const int* __restrict__ src,
                                                 const int* __restrict__ dst,
                                                 const float* __restrict__ mask,
                                                 const int* __restrict__ obase,
                                                 int2* __restrict__ esp,
                                                 int S, int E) {
    __shared__ int lh[MAXBKT];
    int b = blockIdx.x;
    for (int t = threadIdx.x; t < MAXBKT; t += 256) lh[t] = 0;
    __syncthreads();
    int e0 = b * S;
    int e1 = e0 + S < E ? e0 + S : E;
    for (int e = e0 + threadIdx.x; e < e1; e += 256) {
        int d = dst[e];
        int g = d >> DLO_BITS;
        int r = atomicAdd(&lh[g], 1);
        int pos = obase[g * NBLK + b] + r;
        int2 v;
        v.x = src[e] | ((d & (BKT_NODES - 1)) << 17);
        v.y = __float_as_int(mask[e]);
        esp[pos] = v;
    }
}

// P4: one block per bucket. Node counts + degrees (LDS atomics), block scan ->
// row_ptr + dinv, rank pass -> packed CSR esI (src | q15(mask)<<17), then
// fused mirror init: m0[node] = fp16(feat[node] * dinv[node]).
__global__ __launch_bounds__(256) void p4_kernel(const int2* __restrict__ esp,
                                                 const int* __restrict__ obase,
                                                 int* __restrict__ esI,
                                                 int* __restrict__ row_ptr,
                                                 float* __restrict__ dinv,
                                                 const float4* __restrict__ feat,
                                                 uint2* __restrict__ m0,
                                                 int nbkt, int N, int E) {
    __shared__ int lcnt[BKT_NODES];
    __shared__ int lofs[BKT_NODES];
    __shared__ float ldeg[BKT_NODES];
    __shared__ int ws[4];
    int g = blockIdx.x;
    int tid = threadIdx.x;
    lcnt[tid] = 0;
    ldeg[tid] = 0.0f;
    __syncthreads();
    int segbase = obase[g * NBLK];
    int segend = (g + 1 < nbkt) ? obase[(g + 1) * NBLK] : E;
    for (int i = segbase + tid; i < segend; i += 256) {
        int2 v = esp[i];
        int dlo = v.x >> 17;
        atomicAdd(&lcnt[dlo], 1);
        atomicAdd(&ldeg[dlo], __int_as_float(v.y));
    }
    __syncthreads();
    // exclusive scan of lcnt
    int v = lcnt[tid];
    int lane = tid & 63, wv = tid >> 6;
    int x = v;
#pragma unroll
    for (int o = 1; o < 64; o <<= 1) {
        int y = __shfl_up(x, o);
        if (lane >= o) x += y;
    }
    if (lane == 63) ws[wv] = x;
    __syncthreads();
    int add = 0;
    for (int i = 0; i < wv; ++i) add += ws[i];
    x += add;
    int excl = x - v;
    lofs[tid] = excl;
    int node = g * BKT_NODES + tid;
    if (node < N) {
        row_ptr[node] = segbase + excl;
        float d = ldeg[tid];
        d = d > 1.0f ? d : 1.0f;
        float di = 1.0f / sqrtf(d);  // precise: reused across 4 rounds
        dinv[node] = di;
        ldeg[tid] = di;  // ldeg now holds dinv (only tid reads its own slot before this)
    }
    if (g == 0 && tid == 0) row_ptr[N] = E;
    __syncthreads();
    lcnt[tid] = 0;  // reuse as rank counters
    __syncthreads();
    for (int i = segbase + tid; i < segend; i += 256) {
        int2 v2 = esp[i];
        int dlo = v2.x >> 17;
        int r = atomicAdd(&lcnt[dlo], 1);
        float mk = __int_as_float(v2.y);
        int wq = (int)(mk * 32768.0f + 0.5f);
        if (wq > 32767) wq = 32767;
        esI[segbase + lofs[dlo] + r] = (v2.x & 0x1FFFF) | (wq << 17);
    }
    // fused mirror init for this bucket's nodes
    int base_node = g * BKT_NODES;
    for (int t = tid; t < BKT_NODES * 8; t += 256) {
        int nl = t >> 3;
        int n2 = base_node + nl;
        if (n2 >= N) break;
        float di = ldeg[nl];
        float4 f = feat[(size_t)n2 * 8 + (t & 7)];
        __half2 a = __float22half2_rn(make_float2(f.x * di, f.y * di));
        __half2 b = __float22half2_rn(make_float2(f.z * di, f.w * di));
        uint2 m;
        m.x = *(unsigned*)&a;
        m.y = *(unsigned*)&b;
        m0[(size_t)n2 * 8 + (t & 7)] = m;
    }
}

// ---------------- aggregate ----------------
// 2 nodes per wave; 32 lanes per node. c = lane&7 (4-dim column of the 64B
// fp16 row), q = (lane>>3)&3 (4-way edge parallel, 2-deep unroll = 8 gathers
// in flight per node, 16 per wave). Gather pre-scaled by dinv[src];
// edge = packed int {src:17 | q15(mask):15}.
// f_new = fown - (sum_e w_e * m[src_e]) * dinv[n]
// q0: fwr[n] = f_new (fp32 chain)            [not MODE2]
// q1: out update (MODE1: theta0*fav+theta*f; else out += theta*f)
// q2: gout[n] = fp16(f_new * dinv[n])        [not MODE2]
template <int MODE>
__global__ __launch_bounds__(256) void aggregate_kernel(
    const float4* __restrict__ fown, float4* __restrict__ fwr,
    const uint2* __restrict__ gin, uint2* __restrict__ gout,
    float4* __restrict__ out,
    const int* __restrict__ row_ptr, const int* __restrict__ es,
    const float* __restrict__ dinv, float theta, float theta0, int N) {
    int wave = (blockIdx.x * blockDim.x + threadIdx.x) >> 6;
    int lane = threadIdx.x & 63;
    int node = wave * 2 + (lane >> 5);
    if (node >= N) return;
    int lane32 = lane & 31;
    int c = lane32 & 7;
    int q = lane32 >> 3;  // 0..3
    int b = row_ptr[node];
    int e = row_ptr[node + 1];
    float ax = 0.f, ay = 0.f, az = 0.f, aw = 0.f;
    float bx = 0.f, by = 0.f, bz = 0.f, bw = 0.f;
    int i = b + q;
    for (; i + 4 < e; i += 8) {
        int e0 = es[i];
        int e1 = es[i + 4];
        float w0 = (float)((unsigned)e0 >> 17) * (1.0f / 32768.0f);
        float w1 = (float)((unsigned)e1 >> 17) * (1.0f / 32768.0f);
        uint2 r0 = gin[(size_t)(e0 & 0x1FFFF) * 8 + c];
        uint2 r1 = gin[(size_t)(e1 & 0x1FFFF) * 8 + c];
        float2 p0 = __half22float2(*(const __half2*)&r0.x);
        float2 p1 = __half22float2(*(const __half2*)&r0.y);
        float2 p2 = __half22float2(*(const __half2*)&r1.x);
        float2 p3 = __half22float2(*(const __half2*)&r1.y);
        ax += w0 * p0.x; ay += w0 * p0.y; az += w0 * p1.x; aw += w0 * p1.y;
        bx += w1 * p2.x; by += w1 * p2.y; bz += w1 * p3.x; bw += w1 * p3.y;
    }
    if (i < e) {
        int e0 = es[i];
        float w0 = (float)((unsigned)e0 >> 17) * (1.0f / 32768.0f);
        uint2 r0 = gin[(size_t)(e0 & 0x1FFFF) * 8 + c];
        float2 p0 = __half22float2(*(const __half2*)&r0.x);
        float2 p1 = __half22float2(*(const __half2*)&r0.y);
        ax += w0 * p0.x; ay += w0 * p0.y; az += w0 * p1.x; aw += w0 * p1.y;
    }
    ax += bx; ay += by; az += bz; aw += bw;
    // reduce across the 4 q-groups (stays within each 32-lane half)
#pragma unroll
    for (int o = 8; o < 32; o <<= 1) {
        ax += __shfl_xor(ax, o);
        ay += __shfl_xor(ay, o);
        az += __shfl_xor(az, o);
        aw += __shfl_xor(aw, o);
    }
    if (q >= 3) return;
    float4 fav = fown[(size_t)node * 8 + c];
    float di = dinv[node];
    float fx = fav.x - ax * di;
    float fy = fav.y - ay * di;
    float fz = fav.z - az * di;
    float fw = fav.w - aw * di;
    if (MODE != 2) {
        if (q == 0) {
            float4 t; t.x = fx; t.y = fy; t.z = fz; t.w = fw;
            fwr[(size_t)node * 8 + c] = t;
        } else if (q == 1) {
            float4 o;
            if (MODE == 1) {
                o.x = theta0 * fav.x + theta * fx;
                o.y = theta0 * fav.y + theta * fy;
                o.z = theta0 * fav.z + theta * fz;
                o.w = theta0 * fav.w + theta * fw;
            } else {
                o = out[(size_t)node * 8 + c];
                o.x += theta * fx; o.y += theta * fy;
                o.z += theta * fz; o.w += theta * fw;
            }
            out[(size_t)node * 8 + c] = o;
        } else {  // q == 2: next-round fp16 mirror, pre-scaled by dinv[n]
            __half2 a = __float22half2_rn(make_float2(fx * di, fy * di));
            __half2 bb = __float22half2_rn(make_float2(fz * di, fw * di));
            uint2 m;
            m.x = *(unsigned*)&a;
            m.y = *(unsigned*)&bb;
            gout[(size_t)node * 8 + c] = m;
        }
    } else {
        if (q == 1) {
            float4 o = out[(size_t)node * 8 + c];
            o.x += theta * fx; o.y += theta * fy;
            o.z += theta * fz; o.w += theta * fw;
            out[(size_t)node * 8 + c] = o;
        }
    }
}

// ---------------- fallback (small ws / large N): atomic scatter path ----------------

__global__ void fb_deg_kernel(const int* __restrict__ dst, const float* __restrict__ mask,
                              float* __restrict__ deg, int E) {
    int e = blockIdx.x * blockDim.x + threadIdx.x;
    if (e < E) atomicAdd(&deg[dst[e]], mask[e]);
}

__global__ void fb_dinv_kernel(float* __restrict__ deg, int N) {
    int i = blockIdx.x * blockDim.x + threadIdx.x;
    if (i < N) {
        float d = deg[i];
        d = d > 1.0f ? d : 1.0f;
        deg[i] = 1.0f / sqrtf(d);
    }
}

__global__ void fb_init_kernel(const float4* __restrict__ feat, float4* __restrict__ fbuf,
                               float4* __restrict__ out, int n4) {
    int i = blockIdx.x * blockDim.x + threadIdx.x;
    if (i < n4) {
        float4 f = feat[i];
        fbuf[i] = f;
        float4 o;
        o.x = 0.2f * f.x; o.y = 0.2f * f.y; o.z = 0.2f * f.z; o.w = 0.2f * f.w;
        out[i] = o;
    }
}

__global__ void fb_scatter_kernel(const float4* __restrict__ fbuf, const float* __restrict__ dinv,
                                  const int* __restrict__ src, const int* __restrict__ dst,
                                  const float* __restrict__ mask, float* __restrict__ agg, int E) {
    int t = blockIdx.x * blockDim.x + threadIdx.x;
    int e = t >> 3;
    if (e >= E) return;
    int c4 = t & 7;
    int s = src[e];
    int d = dst[e];
    float w = mask[e] * dinv[s];
    float4 f = fbuf[s * 8 + c4];
    float* ap = agg + (size_t)d * FDIM + c4 * 4;
    atomicAdd(ap + 0, f.x * w);
    atomicAdd(ap + 1, f.y * w);
    atomicAdd(ap + 2, f.z * w);
    atomicAdd(ap + 3, f.w * w);
}

__global__ void fb_update_kernel(float4* __restrict__ fbuf, float4* __restrict__ agg,
                                 const float* __restrict__ dinv, float4* __restrict__ out,
                                 float theta, int n4) {
    int t = blockIdx.x * blockDim.x + threadIdx.x;
    if (t >= n4) return;
    int node = t >> 3;
    float di = dinv[node];
    float4 a = agg[t];
    float4 z; z.x = 0.f; z.y = 0.f; z.z = 0.f; z.w = 0.f;
    agg[t] = z;
    float4 f = fbuf[t];
    f.x -= a.x * di; f.y -= a.y * di; f.z -= a.z * di; f.w -= a.w * di;
    fbuf[t] = f;
    float4 o = out[t];
    o.x += theta * f.x; o.y += theta * f.y; o.z += theta * f.z; o.w += theta * f.w;
    out[t] = o;
}

// ---------------- launch ----------------

static inline size_t align_up(size_t x) { return (x + 63) & ~(size_t)63; }  // 64-elem align

extern "C" void kernel_launch(void* const* d_in, const int* in_sizes, int n_in,
                              void* d_out, int out_size, void* d_ws, size_t ws_size,
                              hipStream_t stream) {
    const float* feat = (const float*)d_in[0];
    const int* src = (const int*)d_in[1];
    const int* dst = (const int*)d_in[2];
    const float* mask = (const float*)d_in[3];
    float* out = (float*)d_out;

    const int N = in_sizes[0] / FDIM;
    const int E = in_sizes[1];
    const float thetas[5] = {0.2f, -0.4f, 0.3f, -0.15f, 0.05f};
    const int B = 256;

    const int nbkt = (N + BKT_NODES - 1) / BKT_NODES;
    const int M2 = nbkt * NBLK;
    const int S = (E + NBLK - 1) / NBLK;  // edges per P1/P3 block
    const int nbM2 = (M2 + B - 1) / B;

    // ws layout (4B elements, 64-elem aligned regions).
    // Persistent: dinv, row_ptr, esI. Big overlay region:
    //   build: esp(2E), cntT(M2), obase(M2), bsums(4096)  [+ m0,m1 beyond]
    //   agg:   f(32N), m0(16N), m1(16N)
    size_t o_dinv = 0;                                    // N
    size_t o_rp   = align_up(o_dinv + N);                 // N+1
    size_t o_esI  = align_up(o_rp + N + 1);               // E
    size_t o_big  = align_up(o_esI + (size_t)E);
    size_t o_esp  = o_big;                                // 2E
    size_t o_cntT = align_up(o_esp + 2 * (size_t)E);      // M2
    size_t o_ob   = align_up(o_cntT + (size_t)M2);        // M2
    size_t o_bs   = align_up(o_ob + (size_t)M2);          // 4096
    size_t build_end = o_bs + 4096;
    size_t o_f    = o_big;                                // 32N
    size_t o_m0   = align_up(o_f + (size_t)N * FDIM);     // 16N
    size_t o_m1   = align_up(o_m0 + (size_t)N * 16);      // 16N
    size_t agg_end = o_m1 + (size_t)N * 16;
    size_t need = ((build_end > agg_end ? build_end : agg_end)) * 4;
    // p4 writes m0 while build scratch is live: m0 must not overlap esp/obase.
    // m0 starts at o_big+32N = o_big+2E (since 32N==2E here when E==16N); for
    // safety require m0 region start >= o_bs end or disjoint — checked: m0
    // range [o_m0, agg_end) vs obase/bsums end (build_end). If they overlap,
    // fall back.
    bool m0_safe = (o_m0 >= build_end) || (o_m0 >= o_cntT && false) || (o_m0 >= o_bs + 4096);
    m0_safe = (o_m0 >= build_end);

    float* wsf = (float*)d_ws;
    int* wsi = (int*)d_ws;

    int nbE = (E + B - 1) / B;
    int nbN = (N + B - 1) / B;

    if (ws_size >= need && N <= (1 << 17) && nbkt <= MAXBKT && m0_safe) {
        float* dinv = wsf + o_dinv;
        int* row_ptr = wsi + o_rp;
        int* esI = wsi + o_esI;
        int2* esp = (int2*)(wsi + o_esp);
        int* cntT = wsi + o_cntT;
        int* obase = wsi + o_ob;
        int* bsums = wsi + o_bs;
        float4* f = (float4*)(wsf + o_f);
        uint2* m0 = (uint2*)(wsi + o_m0);
        uint2* m1 = (uint2*)(wsi + o_m1);

        p1_kernel<<<NBLK, B, 0, stream>>>(dst, cntT, nbkt, S, E);
        scanA_kernel<<<nbM2, B, 0, stream>>>(cntT, obase, bsums, M2);
        scan2_kernel<<<1, 512, 0, stream>>>(bsums, nbM2);
        scanC_kernel<<<nbM2, B, 0, stream>>>(obase, bsums, M2);
        p3_kernel<<<NBLK, B, 0, stream>>>(src, dst, mask, obase, esp, S, E);
        p4_kernel<<<nbkt, B, 0, stream>>>(esp, obase, esI, row_ptr, dinv,
                                          (const float4*)feat, m0, nbkt, N, E);

        int aggWaves = (N + 1) / 2;
        int agg_blocks = (aggWaves * 64 + B - 1) / B;
        // r1: own=feat, chain->f, gather m0 -> write m1, out = th0*feat + th1*f1
        aggregate_kernel<1><<<agg_blocks, B, 0, stream>>>((const float4*)feat, f, m0, m1,
                                                          (float4*)out, row_ptr, esI, dinv,
                                                          thetas[1], thetas[0], N);
        // r2: own=f in-place, gather m1 -> write m0
        aggregate_kernel<0><<<agg_blocks, B, 0, stream>>>(f, f, m1, m0, (float4*)out,
                                                          row_ptr, esI, dinv, thetas[2], 0.f, N);
        // r3: own=f in-place, gather m0 -> write m1
        aggregate_kernel<0><<<agg_blocks, B, 0, stream>>>(f, f, m0, m1, (float4*)out,
                                                          row_ptr, esI, dinv, thetas[3], 0.f, N);
        // r4: own=f, gather m1, out only
        aggregate_kernel<2><<<agg_blocks, B, 0, stream>>>(f, f, m1, m0, (float4*)out,
                                                          row_ptr, esI, dinv, thetas[4], 0.f, N);
    } else {
        // fallback: atomic-scatter path
        float* deg = wsf;                       // N
        float* agg = deg + align_up(N);         // 32N
        float* fbuf = agg + (size_t)N * FDIM;   // 32N

        hipMemsetAsync(d_ws, 0, (align_up(N) + (size_t)N * FDIM) * 4, stream);
        fb_deg_kernel<<<nbE, B, 0, stream>>>(dst, mask, deg, E);
        fb_dinv_kernel<<<nbN, B, 0, stream>>>(deg, N);

        int n4 = N * (FDIM / 4);
        fb_init_kernel<<<(n4 + B - 1) / B, B, 0, stream>>>((const float4*)feat, (float4*)fbuf,
                                                           (float4*)out, n4);
        long long sc_threads = (long long)E * 8;
        int sc_blocks = (int)((sc_threads + B - 1) / B);
        for (int k = 1; k < 5; ++k) {
            fb_scatter_kernel<<<sc_blocks, B, 0, stream>>>((const float4*)fbuf, deg, src, dst,
                                                           mask, agg, E);
            fb_update_kernel<<<(n4 + B - 1) / B, B, 0, stream>>>((float4*)fbuf, (float4*)agg,
                                                                 deg, (float4*)out, thetas[k], n4);
        }
    }
}

// Round 10
// 195.369 us; speedup vs baseline: 13.9408x; 13.9408x over previous
//
#include <hip/hip_runtime.h>
#include <hip/hip_fp16.h>

// PolyConv via CSR-gather. Build = LDS counting sort (no global atomics),
// packed 4B edge records {src:17 | q15(mask):15}, fp16 gather mirror
// pre-scaled by dinv[src] (ping-pong m0/m1, persistent), in-place fp32 chain.
// Aggregate: 2 nodes per wave (32 lanes each).
// feat [N,32] f32, src [E] i32, dst [E] i32, mask [E] f32 -> h [N,32] f32.

#define FDIM 32
#define DLO_BITS 8
#define BKT_NODES 256          // nodes per bucket = 1<<DLO_BITS
#define NBLK 512               // partition blocks for P1/P3
#define MAXBKT 512             // supports N <= 131072 (src fits 17 bits)

// ---------------- build ----------------

// P1: per-block bucket histogram. cntT[g*NBLK + b].
__global__ __launch_bounds__(256) void p1_kernel(const int* __restrict__ dst,
                                                 int* __restrict__ cntT,
                                                 int nbkt, int S, int E) {
    __shared__ int lh[MAXBKT];
    int b = blockIdx.x;
    for (int t = threadIdx.x; t < MAXBKT; t += 256) lh[t] = 0;
    __syncthreads();
    int e0 = b * S;
    int e1 = e0 + S < E ? e0 + S : E;
    for (int e = e0 + threadIdx.x; e < e1; e += 256)
        atomicAdd(&lh[dst[e] >> DLO_BITS], 1);
    __syncthreads();
    for (int t = threadIdx.x; t < nbkt; t += 256) cntT[t * NBLK + b] = lh[t];
}

// generic exclusive block scan (256/block) of cntT -> obase, block sums -> bsums
__global__ void scanA_kernel(const int* __restrict__ cntT, int* __restrict__ obase,
                             int* __restrict__ bsums, int M2) {
    int tid = threadIdx.x;
    int gid = blockIdx.x * 256 + tid;
    int v = (gid < M2) ? cntT[gid] : 0;
    int lane = tid & 63, wv = tid >> 6;
    int x = v;
#pragma unroll
    for (int o = 1; o < 64; o <<= 1) {
        int y = __shfl_up(x, o);
        if (lane >= o) x += y;
    }
    __shared__ int ws[4];
    if (lane == 63) ws[wv] = x;
    __syncthreads();
    int add = 0;
    for (int i = 0; i < wv; ++i) add += ws[i];
    x += add;
    if (gid < M2) obase[gid] = x - v;
    if (tid == 255) bsums[blockIdx.x] = x;
}

// single block (512 threads), scans bsums in place (exclusive), loops if nb>512
__global__ void scan2_kernel(int* __restrict__ bsums, int nb) {
    __shared__ int ws[8];
    __shared__ int carry;
    if (threadIdx.x == 0) carry = 0;
    __syncthreads();
    for (int base = 0; base < nb; base += 512) {
        int i = base + threadIdx.x;
        int v = (i < nb) ? bsums[i] : 0;
        int lane = threadIdx.x & 63, wv = threadIdx.x >> 6;
        int x = v;
#pragma unroll
        for (int o = 1; o < 64; o <<= 1) {
            int y = __shfl_up(x, o);
            if (lane >= o) x += y;
        }
        if (lane == 63) ws[wv] = x;
        __syncthreads();
        int add = 0;
        for (int j = 0; j < wv; ++j) add += ws[j];
        x += add;
        int c = carry;
        if (i < nb) bsums[i] = x - v + c;
        __syncthreads();
        if (threadIdx.x == 511) carry = c + x;
        __syncthreads();
    }
}

__global__ void scanC_kernel(int* __restrict__ obase, const int* __restrict__ bsums, int M2) {
    int gid = blockIdx.x * 256 + threadIdx.x;
    if (gid < M2) obase[gid] += bsums[blockIdx.x];
}

// P3: bucket-partition scatter. Same partition as P1; LDS rank within (block,bucket).
// esp[pos] = { src | (dlo<<17), bits(mask) }.
__global__ __launch_bounds__(256) void p3_kernel(const int* __restrict__ src,
                                                 const int* __restrict__ dst,
                                                 const float* __restrict__ mask,
                                                 const int* __restrict__ obase,
                                                 int2* __restrict__ esp,
                                                 int S, int E) {
    __shared__ int lh[MAXBKT];
    int b = blockIdx.x;
    for (int t = threadIdx.x; t < MAXBKT; t += 256) lh[t] = 0;
    __syncthreads();
    int e0 = b * S;
    int e1 = e0 + S < E ? e0 + S : E;
    for (int e = e0 + threadIdx.x; e < e1; e += 256) {
        int d = dst[e];
        int g = d >> DLO_BITS;
        int r = atomicAdd(&lh[g], 1);
        int pos = obase[g * NBLK + b] + r;
        int2 v;
        v.x = src[e] | ((d & (BKT_NODES - 1)) << 17);
        v.y = __float_as_int(mask[e]);
        esp[pos] = v;
    }
}

// P4: one block per bucket. Node counts + degrees (LDS atomics), block scan ->
// row_ptr + dinv, rank pass -> packed CSR esI (src | q15(mask)<<17), then
// fused mirror init: m0[node] = fp16(feat[node] * dinv[node]).
// m0 is a PERSISTENT region (no overlap with esp/obase).
__global__ __launch_bounds__(256) void p4_kernel(const int2* __restrict__ esp,
                                                 const int* __restrict__ obase,
                                                 int* __restrict__ esI,
                                                 int* __restrict__ row_ptr,
                                                 float* __restrict__ dinv,
                                                 const float4* __restrict__ feat,
                                                 uint2* __restrict__ m0,
                                                 int nbkt, int N, int E) {
    __shared__ int lcnt[BKT_NODES];
    __shared__ int lofs[BKT_NODES];
    __shared__ float ldeg[BKT_NODES];
    __shared__ int ws[4];
    int g = blockIdx.x;
    int tid = threadIdx.x;
    lcnt[tid] = 0;
    ldeg[tid] = 0.0f;
    __syncthreads();
    int segbase = obase[g * NBLK];
    int segend = (g + 1 < nbkt) ? obase[(g + 1) * NBLK] : E;
    for (int i = segbase + tid; i < segend; i += 256) {
        int2 v = esp[i];
        int dlo = v.x >> 17;
        atomicAdd(&lcnt[dlo], 1);
        atomicAdd(&ldeg[dlo], __int_as_float(v.y));
    }
    __syncthreads();
    // exclusive scan of lcnt
    int v = lcnt[tid];
    int lane = tid & 63, wv = tid >> 6;
    int x = v;
#pragma unroll
    for (int o = 1; o < 64; o <<= 1) {
        int y = __shfl_up(x, o);
        if (lane >= o) x += y;
    }
    if (lane == 63) ws[wv] = x;
    __syncthreads();
    int add = 0;
    for (int i = 0; i < wv; ++i) add += ws[i];
    x += add;
    int excl = x - v;
    lofs[tid] = excl;
    int node = g * BKT_NODES + tid;
    if (node < N) {
        row_ptr[node] = segbase + excl;
        float d = ldeg[tid];
        d = d > 1.0f ? d : 1.0f;
        float di = 1.0f / sqrtf(d);  // precise: reused across 4 rounds
        dinv[node] = di;
        ldeg[tid] = di;  // ldeg now holds dinv (own slot only; synced below)
    }
    if (g == 0 && tid == 0) row_ptr[N] = E;
    __syncthreads();
    lcnt[tid] = 0;  // reuse as rank counters
    __syncthreads();
    for (int i = segbase + tid; i < segend; i += 256) {
        int2 v2 = esp[i];
        int dlo = v2.x >> 17;
        int r = atomicAdd(&lcnt[dlo], 1);
        float mk = __int_as_float(v2.y);
        int wq = (int)(mk * 32768.0f + 0.5f);
        if (wq > 32767) wq = 32767;
        esI[segbase + lofs[dlo] + r] = (v2.x & 0x1FFFF) | (wq << 17);
    }
    // fused mirror init for this bucket's nodes (ldeg holds dinv; synced above)
    int base_node = g * BKT_NODES;
    for (int t = tid; t < BKT_NODES * 8; t += 256) {
        int nl = t >> 3;
        int n2 = base_node + nl;
        if (n2 >= N) break;
        float di = ldeg[nl];
        float4 f = feat[(size_t)n2 * 8 + (t & 7)];
        __half2 a = __float22half2_rn(make_float2(f.x * di, f.y * di));
        __half2 b = __float22half2_rn(make_float2(f.z * di, f.w * di));
        uint2 m;
        m.x = *(unsigned*)&a;
        m.y = *(unsigned*)&b;
        m0[(size_t)n2 * 8 + (t & 7)] = m;
    }
}

// ---------------- aggregate ----------------
// 2 nodes per wave; 32 lanes per node. c = lane&7 (4-dim column of the 64B
// fp16 row), q = (lane>>3)&3 (4-way edge parallel, 2-deep unroll = 8 gathers
// in flight per node, 16 per wave). Gather pre-scaled by dinv[src];
// edge = packed int {src:17 | q15(mask):15}.
// f_new = fown - (sum_e w_e * m[src_e]) * dinv[n]
// q0: fwr[n] = f_new (fp32 chain)            [not MODE2]
// q1: out update (MODE1: theta0*fav+theta*f; else out += theta*f)
// q2: gout[n] = fp16(f_new * dinv[n])        [not MODE2]
template <int MODE>
__global__ __launch_bounds__(256) void aggregate_kernel(
    const float4* __restrict__ fown, float4* __restrict__ fwr,
    const uint2* __restrict__ gin, uint2* __restrict__ gout,
    float4* __restrict__ out,
    const int* __restrict__ row_ptr, const int* __restrict__ es,
    const float* __restrict__ dinv, float theta, float theta0, int N) {
    int wave = (blockIdx.x * blockDim.x + threadIdx.x) >> 6;
    int lane = threadIdx.x & 63;
    int node = wave * 2 + (lane >> 5);
    if (node >= N) return;
    int lane32 = lane & 31;
    int c = lane32 & 7;
    int q = lane32 >> 3;  // 0..3
    int b = row_ptr[node];
    int e = row_ptr[node + 1];
    float ax = 0.f, ay = 0.f, az = 0.f, aw = 0.f;
    float bx = 0.f, by = 0.f, bz = 0.f, bw = 0.f;
    int i = b + q;
    for (; i + 4 < e; i += 8) {
        int e0 = es[i];
        int e1 = es[i + 4];
        float w0 = (float)((unsigned)e0 >> 17) * (1.0f / 32768.0f);
        float w1 = (float)((unsigned)e1 >> 17) * (1.0f / 32768.0f);
        uint2 r0 = gin[(size_t)(e0 & 0x1FFFF) * 8 + c];
        uint2 r1 = gin[(size_t)(e1 & 0x1FFFF) * 8 + c];
        float2 p0 = __half22float2(*(const __half2*)&r0.x);
        float2 p1 = __half22float2(*(const __half2*)&r0.y);
        float2 p2 = __half22float2(*(const __half2*)&r1.x);
        float2 p3 = __half22float2(*(const __half2*)&r1.y);
        ax += w0 * p0.x; ay += w0 * p0.y; az += w0 * p1.x; aw += w0 * p1.y;
        bx += w1 * p2.x; by += w1 * p2.y; bz += w1 * p3.x; bw += w1 * p3.y;
    }
    if (i < e) {
        int e0 = es[i];
        float w0 = (float)((unsigned)e0 >> 17) * (1.0f / 32768.0f);
        uint2 r0 = gin[(size_t)(e0 & 0x1FFFF) * 8 + c];
        float2 p0 = __half22float2(*(const __half2*)&r0.x);
        float2 p1 = __half22float2(*(const __half2*)&r0.y);
        ax += w0 * p0.x; ay += w0 * p0.y; az += w0 * p1.x; aw += w0 * p1.y;
    }
    ax += bx; ay += by; az += bz; aw += bw;
    // reduce across the 4 q-groups (xor 8,16 stays within each 32-lane half)
#pragma unroll
    for (int o = 8; o < 32; o <<= 1) {
        ax += __shfl_xor(ax, o);
        ay += __shfl_xor(ay, o);
        az += __shfl_xor(az, o);
        aw += __shfl_xor(aw, o);
    }
    if (q >= 3) return;
    float4 fav = fown[(size_t)node * 8 + c];
    float di = dinv[node];
    float fx = fav.x - ax * di;
    float fy = fav.y - ay * di;
    float fz = fav.z - az * di;
    float fw = fav.w - aw * di;
    if (MODE != 2) {
        if (q == 0) {
            float4 t; t.x = fx; t.y = fy; t.z = fz; t.w = fw;
            fwr[(size_t)node * 8 + c] = t;
        } else if (q == 1) {
            float4 o;
            if (MODE == 1) {
                o.x = theta0 * fav.x + theta * fx;
                o.y = theta0 * fav.y + theta * fy;
                o.z = theta0 * fav.z + theta * fz;
                o.w = theta0 * fav.w + theta * fw;
            } else {
                o = out[(size_t)node * 8 + c];
                o.x += theta * fx; o.y += theta * fy;
                o.z += theta * fz; o.w += theta * fw;
            }
            out[(size_t)node * 8 + c] = o;
        } else {  // q == 2: next-round fp16 mirror, pre-scaled by dinv[n]
            __half2 a = __float22half2_rn(make_float2(fx * di, fy * di));
            __half2 bb = __float22half2_rn(make_float2(fz * di, fw * di));
            uint2 m;
            m.x = *(unsigned*)&a;
            m.y = *(unsigned*)&bb;
            gout[(size_t)node * 8 + c] = m;
        }
    } else {
        if (q == 1) {
            float4 o = out[(size_t)node * 8 + c];
            o.x += theta * fx; o.y += theta * fy;
            o.z += theta * fz; o.w += theta * fw;
            out[(size_t)node * 8 + c] = o;
        }
    }
}

// ---------------- fallback (small ws / large N): atomic scatter path ----------------

__global__ void fb_deg_kernel(const int* __restrict__ dst, const float* __restrict__ mask,
                              float* __restrict__ deg, int E) {
    int e = blockIdx.x * blockDim.x + threadIdx.x;
    if (e < E) atomicAdd(&deg[dst[e]], mask[e]);
}

__global__ void fb_dinv_kernel(float* __restrict__ deg, int N) {
    int i = blockIdx.x * blockDim.x + threadIdx.x;
    if (i < N) {
        float d = deg[i];
        d = d > 1.0f ? d : 1.0f;
        deg[i] = 1.0f / sqrtf(d);
    }
}

__global__ void fb_init_kernel(const float4* __restrict__ feat, float4* __restrict__ fbuf,
                               float4* __restrict__ out, int n4) {
    int i = blockIdx.x * blockDim.x + threadIdx.x;
    if (i < n4) {
        float4 f = feat[i];
        fbuf[i] = f;
        float4 o;
        o.x = 0.2f * f.x; o.y = 0.2f * f.y; o.z = 0.2f * f.z; o.w = 0.2f * f.w;
        out[i] = o;
    }
}

__global__ void fb_scatter_kernel(const float4* __restrict__ fbuf, const float* __restrict__ dinv,
                                  const int* __restrict__ src, const int* __restrict__ dst,
                                  const float* __restrict__ mask, float* __restrict__ agg, int E) {
    int t = blockIdx.x * blockDim.x + threadIdx.x;
    int e = t >> 3;
    if (e >= E) return;
    int c4 = t & 7;
    int s = src[e];
    int d = dst[e];
    float w = mask[e] * dinv[s];
    float4 f = fbuf[s * 8 + c4];
    float* ap = agg + (size_t)d * FDIM + c4 * 4;
    atomicAdd(ap + 0, f.x * w);
    atomicAdd(ap + 1, f.y * w);
    atomicAdd(ap + 2, f.z * w);
    atomicAdd(ap + 3, f.w * w);
}

__global__ void fb_update_kernel(float4* __restrict__ fbuf, float4* __restrict__ agg,
                                 const float* __restrict__ dinv, float4* __restrict__ out,
                                 float theta, int n4) {
    int t = blockIdx.x * blockDim.x + threadIdx.x;
    if (t >= n4) return;
    int node = t >> 3;
    float di = dinv[node];
    float4 a = agg[t];
    float4 z; z.x = 0.f; z.y = 0.f; z.z = 0.f; z.w = 0.f;
    agg[t] = z;
    float4 f = fbuf[t];
    f.x -= a.x * di; f.y -= a.y * di; f.z -= a.z * di; f.w -= a.w * di;
    fbuf[t] = f;
    float4 o = out[t];
    o.x += theta * f.x; o.y += theta * f.y; o.z += theta * f.z; o.w += theta * f.w;
    out[t] = o;
}

// ---------------- launch ----------------

static inline size_t align_up(size_t x) { return (x + 63) & ~(size_t)63; }  // 64-elem align

extern "C" void kernel_launch(void* const* d_in, const int* in_sizes, int n_in,
                              void* d_out, int out_size, void* d_ws, size_t ws_size,
                              hipStream_t stream) {
    const float* feat = (const float*)d_in[0];
    const int* src = (const int*)d_in[1];
    const int* dst = (const int*)d_in[2];
    const float* mask = (const float*)d_in[3];
    float* out = (float*)d_out;

    const int N = in_sizes[0] / FDIM;
    const int E = in_sizes[1];
    const float thetas[5] = {0.2f, -0.4f, 0.3f, -0.15f, 0.05f};
    const int B = 256;

    const int nbkt = (N + BKT_NODES - 1) / BKT_NODES;
    const int M2 = nbkt * NBLK;
    const int S = (E + NBLK - 1) / NBLK;  // edges per P1/P3 block
    const int nbM2 = (M2 + B - 1) / B;

    // ws layout (4B elements, 64-elem aligned regions).
    // Persistent: dinv, row_ptr, esI, m0, m1 (m0 written by p4 -> persistent,
    // MUST NOT overlap build scratch; R9 bug). Overlay region o_big:
    //   build: esp(2E), cntT(M2), obase(M2), bsums(4096)
    //   agg:   f(32N)   [f first written in round 1, after build is dead]
    size_t o_dinv = 0;                                    // N
    size_t o_rp   = align_up(o_dinv + N);                 // N+1
    size_t o_esI  = align_up(o_rp + N + 1);               // E
    size_t o_m0   = align_up(o_esI + (size_t)E);          // 16N
    size_t o_m1   = align_up(o_m0 + (size_t)N * 16);      // 16N
    size_t o_big  = align_up(o_m1 + (size_t)N * 16);
    size_t o_esp  = o_big;                                // 2E
    size_t o_cntT = align_up(o_esp + 2 * (size_t)E);      // M2
    size_t o_ob   = align_up(o_cntT + (size_t)M2);        // M2
    size_t o_bs   = align_up(o_ob + (size_t)M2);          // 4096
    size_t build_end = o_bs + 4096;
    size_t o_f    = o_big;                                // 32N
    size_t agg_end = o_f + (size_t)N * FDIM;
    size_t need = (build_end > agg_end ? build_end : agg_end) * 4;

    float* wsf = (float*)d_ws;
    int* wsi = (int*)d_ws;

    int nbE = (E + B - 1) / B;
    int nbN = (N + B - 1) / B;

    if (ws_size >= need && N <= (1 << 17) && nbkt <= MAXBKT) {
        float* dinv = wsf + o_dinv;
        int* row_ptr = wsi + o_rp;
        int* esI = wsi + o_esI;
        uint2* m0 = (uint2*)(wsi + o_m0);
        uint2* m1 = (uint2*)(wsi + o_m1);
        int2* esp = (int2*)(wsi + o_esp);
        int* cntT = wsi + o_cntT;
        int* obase = wsi + o_ob;
        int* bsums = wsi + o_bs;
        float4* f = (float4*)(wsf + o_f);

        p1_kernel<<<NBLK, B, 0, stream>>>(dst, cntT, nbkt, S, E);
        scanA_kernel<<<nbM2, B, 0, stream>>>(cntT, obase, bsums, M2);
        scan2_kernel<<<1, 512, 0, stream>>>(bsums, nbM2);
        scanC_kernel<<<nbM2, B, 0, stream>>>(obase, bsums, M2);
        p3_kernel<<<NBLK, B, 0, stream>>>(src, dst, mask, obase, esp, S, E);
        p4_kernel<<<nbkt, B, 0, stream>>>(esp, obase, esI, row_ptr, dinv,
                                          (const float4*)feat, m0, nbkt, N, E);

        int aggWaves = (N + 1) / 2;
        int agg_blocks = (aggWaves * 64 + B - 1) / B;
        // r1: own=feat, chain->f, gather m0 -> write m1, out = th0*feat + th1*f1
        aggregate_kernel<1><<<agg_blocks, B, 0, stream>>>((const float4*)feat, f, m0, m1,
                                                          (float4*)out, row_ptr, esI, dinv,
                                                          thetas[1], thetas[0], N);
        // r2: own=f in-place, gather m1 -> write m0
        aggregate_kernel<0><<<agg_blocks, B, 0, stream>>>(f, f, m1, m0, (float4*)out,
                                                          row_ptr, esI, dinv, thetas[2], 0.f, N);
        // r3: own=f in-place, gather m0 -> write m1
        aggregate_kernel<0><<<agg_blocks, B, 0, stream>>>(f, f, m0, m1, (float4*)out,
                                                          row_ptr, esI, dinv, thetas[3], 0.f, N);
        // r4: own=f, gather m1, out only
        aggregate_kernel<2><<<agg_blocks, B, 0, stream>>>(f, f, m1, m0, (float4*)out,
                                                          row_ptr, esI, dinv, thetas[4], 0.f, N);
    } else {
        // fallback: atomic-scatter path
        float* deg = wsf;                       // N
        float* agg = deg + align_up(N);         // 32N
        float* fbuf = agg + (size_t)N * FDIM;   // 32N

        hipMemsetAsync(d_ws, 0, (align_up(N) + (size_t)N * FDIM) * 4, stream);
        fb_deg_kernel<<<nbE, B, 0, stream>>>(dst, mask, deg, E);
        fb_dinv_kernel<<<nbN, B, 0, stream>>>(deg, N);

        int n4 = N * (FDIM / 4);
        fb_init_kernel<<<(n4 + B - 1) / B, B, 0, stream>>>((const float4*)feat, (float4*)fbuf,
                                                           (float4*)out, n4);
        long long sc_threads = (long long)E * 8;
        int sc_blocks = (int)((sc_threads + B - 1) / B);
        for (int k = 1; k < 5; ++k) {
            fb_scatter_kernel<<<sc_blocks, B, 0, stream>>>((const float4*)fbuf, deg, src, dst,
                                                           mask, agg, E);
            fb_update_kernel<<<(n4 + B - 1) / B, B, 0, stream>>>((float4*)fbuf, (float4*)agg,
                                                                 deg, (float4*)out, thetas[k], n4);
        }
    }
}

// Round 11
// 194.284 us; speedup vs baseline: 14.0186x; 1.0056x over previous
//
#include <hip/hip_runtime.h>
#include <hip/hip_fp16.h>

// PolyConv via CSR-gather. Build = LDS counting sort (no global atomics),
// packed 4B edge records {src:17 | q15(mask):15}, fp16 gather mirror
// pre-scaled by dinv[src] (ping-pong m0/m1, persistent), in-place fp32 chain.
// Aggregate: 4 nodes per wave (16 lanes each).
// feat [N,32] f32, src [E] i32, dst [E] i32, mask [E] f32 -> h [N,32] f32.

#define FDIM 32
#define DLO_BITS 8
#define BKT_NODES 256          // nodes per bucket = 1<<DLO_BITS
#define NBLK 1024              // partition blocks for P1/P3 (4 blocks/CU)
#define MAXBKT 512             // supports N <= 131072 (src fits 17 bits)

// ---------------- build ----------------

// P1: per-block bucket histogram. cntT[g*NBLK + b].
__global__ __launch_bounds__(256) void p1_kernel(const int* __restrict__ dst,
                                                 int* __restrict__ cntT,
                                                 int nbkt, int S, int E) {
    __shared__ int lh[MAXBKT];
    int b = blockIdx.x;
    for (int t = threadIdx.x; t < MAXBKT; t += 256) lh[t] = 0;
    __syncthreads();
    int e0 = b * S;
    int e1 = e0 + S < E ? e0 + S : E;
    for (int e = e0 + threadIdx.x; e < e1; e += 256)
        atomicAdd(&lh[dst[e] >> DLO_BITS], 1);
    __syncthreads();
    for (int t = threadIdx.x; t < nbkt; t += 256) cntT[t * NBLK + b] = lh[t];
}

// generic exclusive block scan (256/block) of cntT -> obase, block sums -> bsums
__global__ void scanA_kernel(const int* __restrict__ cntT, int* __restrict__ obase,
                             int* __restrict__ bsums, int M2) {
    int tid = threadIdx.x;
    int gid = blockIdx.x * 256 + tid;
    int v = (gid < M2) ? cntT[gid] : 0;
    int lane = tid & 63, wv = tid >> 6;
    int x = v;
#pragma unroll
    for (int o = 1; o < 64; o <<= 1) {
        int y = __shfl_up(x, o);
        if (lane >= o) x += y;
    }
    __shared__ int ws[4];
    if (lane == 63) ws[wv] = x;
    __syncthreads();
    int add = 0;
    for (int i = 0; i < wv; ++i) add += ws[i];
    x += add;
    if (gid < M2) obase[gid] = x - v;
    if (tid == 255) bsums[blockIdx.x] = x;
}

// single block (512 threads), scans bsums in place (exclusive), loops if nb>512
__global__ void scan2_kernel(int* __restrict__ bsums, int nb) {
    __shared__ int ws[8];
    __shared__ int carry;
    if (threadIdx.x == 0) carry = 0;
    __syncthreads();
    for (int base = 0; base < nb; base += 512) {
        int i = base + threadIdx.x;
        int v = (i < nb) ? bsums[i] : 0;
        int lane = threadIdx.x & 63, wv = threadIdx.x >> 6;
        int x = v;
#pragma unroll
        for (int o = 1; o < 64; o <<= 1) {
            int y = __shfl_up(x, o);
            if (lane >= o) x += y;
        }
        if (lane == 63) ws[wv] = x;
        __syncthreads();
        int add = 0;
        for (int j = 0; j < wv; ++j) add += ws[j];
        x += add;
        int c = carry;
        if (i < nb) bsums[i] = x - v + c;
        __syncthreads();
        if (threadIdx.x == 511) carry = c + x;
        __syncthreads();
    }
}

__global__ void scanC_kernel(int* __restrict__ obase, const int* __restrict__ bsums, int M2) {
    int gid = blockIdx.x * 256 + threadIdx.x;
    if (gid < M2) obase[gid] += bsums[blockIdx.x];
}

// P3: bucket-partition scatter. Same partition as P1; LDS rank within (block,bucket).
// esp[pos] = { src | (dlo<<17), bits(mask) }.
__global__ __launch_bounds__(256) void p3_kernel(const int* __restrict__ src,
                                                 const int* __restrict__ dst,
                                                 const float* __restrict__ mask,
                                                 const int* __restrict__ obase,
                                                 int2* __restrict__ esp,
                                                 int S, int E) {
    __shared__ int lh[MAXBKT];
    int b = blockIdx.x;
    for (int t = threadIdx.x; t < MAXBKT; t += 256) lh[t] = 0;
    __syncthreads();
    int e0 = b * S;
    int e1 = e0 + S < E ? e0 + S : E;
    for (int e = e0 + threadIdx.x; e < e1; e += 256) {
        int d = dst[e];
        int g = d >> DLO_BITS;
        int r = atomicAdd(&lh[g], 1);
        int pos = obase[g * NBLK + b] + r;
        int2 v;
        v.x = src[e] | ((d & (BKT_NODES - 1)) << 17);
        v.y = __float_as_int(mask[e]);
        esp[pos] = v;
    }
}

// P4: one 512-thread block per bucket. Node counts + degrees (LDS atomics),
// zero-padded block scan -> row_ptr + dinv, rank pass -> packed CSR esI
// (src | q15(mask)<<17), then fused mirror init m0 = fp16(feat*dinv).
__global__ __launch_bounds__(512) void p4_kernel(const int2* __restrict__ esp,
                                                 const int* __restrict__ obase,
                                                 int* __restrict__ esI,
                                                 int* __restrict__ row_ptr,
                                                 float* __restrict__ dinv,
                                                 const float4* __restrict__ feat,
                                                 uint2* __restrict__ m0,
                                                 int nbkt, int N, int E) {
    __shared__ int lcnt[BKT_NODES];
    __shared__ int lofs[BKT_NODES];
    __shared__ float ldeg[BKT_NODES];
    __shared__ int ws[8];
    int g = blockIdx.x;
    int tid = threadIdx.x;
    if (tid < BKT_NODES) { lcnt[tid] = 0; ldeg[tid] = 0.0f; }
    __syncthreads();
    int segbase = obase[g * NBLK];
    int segend = (g + 1 < nbkt) ? obase[(g + 1) * NBLK] : E;
    for (int i = segbase + tid; i < segend; i += 512) {
        int2 v = esp[i];
        int dlo = v.x >> 17;
        atomicAdd(&lcnt[dlo], 1);
        atomicAdd(&ldeg[dlo], __int_as_float(v.y));
    }
    __syncthreads();
    // 512-wide exclusive scan, zero-padded past BKT_NODES
    int v = (tid < BKT_NODES) ? lcnt[tid] : 0;
    int lane = tid & 63, wv = tid >> 6;
    int x = v;
#pragma unroll
    for (int o = 1; o < 64; o <<= 1) {
        int y = __shfl_up(x, o);
        if (lane >= o) x += y;
    }
    if (lane == 63) ws[wv] = x;
    __syncthreads();
    int add = 0;
    for (int i = 0; i < wv; ++i) add += ws[i];
    x += add;
    int excl = x - v;
    if (tid < BKT_NODES) {
        lofs[tid] = excl;
        int node = g * BKT_NODES + tid;
        if (node < N) {
            row_ptr[node] = segbase + excl;
            float d = ldeg[tid];
            d = d > 1.0f ? d : 1.0f;
            float di = 1.0f / sqrtf(d);  // precise: reused across 4 rounds
            dinv[node] = di;
            ldeg[tid] = di;  // ldeg now holds dinv (own slot only; synced below)
        }
    }
    if (g == 0 && tid == 0) row_ptr[N] = E;
    __syncthreads();
    if (tid < BKT_NODES) lcnt[tid] = 0;  // reuse as rank counters
    __syncthreads();
    for (int i = segbase + tid; i < segend; i += 512) {
        int2 v2 = esp[i];
        int dlo = v2.x >> 17;
        int r = atomicAdd(&lcnt[dlo], 1);
        float mk = __int_as_float(v2.y);
        int wq = (int)(mk * 32768.0f + 0.5f);
        if (wq > 32767) wq = 32767;
        esI[segbase + lofs[dlo] + r] = (v2.x & 0x1FFFF) | (wq << 17);
    }
    // fused mirror init for this bucket's nodes (ldeg holds dinv; synced above)
    int base_node = g * BKT_NODES;
    for (int t = tid; t < BKT_NODES * 8; t += 512) {
        int nl = t >> 3;
        int n2 = base_node + nl;
        if (n2 >= N) break;
        float di = ldeg[nl];
        float4 f = feat[(size_t)n2 * 8 + (t & 7)];
        __half2 a = __float22half2_rn(make_float2(f.x * di, f.y * di));
        __half2 b = __float22half2_rn(make_float2(f.z * di, f.w * di));
        uint2 m;
        m.x = *(unsigned*)&a;
        m.y = *(unsigned*)&b;
        m0[(size_t)n2 * 8 + (t & 7)] = m;
    }
}

// ---------------- aggregate ----------------
// 4 nodes per wave; 16 lanes per node. c = lane&7 (uint2 chunk of the 64B
// fp16 row), q = (lane>>3)&1 (2-way edge parallel, 2-deep unroll = 4 gathers
// in flight per node, 16 per wave). Gather pre-scaled by dinv[src];
// edge = packed int {src:17 | q15(mask):15}.
// f_new = fown - (sum_e w_e * m[src_e]) * dinv[n]
// q0: fwr[n] = f_new (fp32 chain) + gout[n] = fp16(f_new*dinv) [not MODE2]
// q1: out update (MODE1: theta0*fav+theta*f; else out += theta*f)
template <int MODE>
__global__ __launch_bounds__(256) void aggregate_kernel(
    const float4* __restrict__ fown, float4* __restrict__ fwr,
    const uint2* __restrict__ gin, uint2* __restrict__ gout,
    float4* __restrict__ out,
    const int* __restrict__ row_ptr, const int* __restrict__ es,
    const float* __restrict__ dinv, float theta, float theta0, int N) {
    int wave = (blockIdx.x * blockDim.x + threadIdx.x) >> 6;
    int lane = threadIdx.x & 63;
    int node = wave * 4 + (lane >> 4);
    if (node >= N) return;
    int l16 = lane & 15;
    int c = l16 & 7;
    int q = l16 >> 3;  // 0..1
    int b = row_ptr[node];
    int e = row_ptr[node + 1];
    float ax = 0.f, ay = 0.f, az = 0.f, aw = 0.f;
    float bx = 0.f, by = 0.f, bz = 0.f, bw = 0.f;
    int i = b + q;
    for (; i + 2 < e; i += 4) {
        int e0 = es[i];
        int e1 = es[i + 2];
        float w0 = (float)((unsigned)e0 >> 17) * (1.0f / 32768.0f);
        float w1 = (float)((unsigned)e1 >> 17) * (1.0f / 32768.0f);
        uint2 r0 = gin[(size_t)(e0 & 0x1FFFF) * 8 + c];
        uint2 r1 = gin[(size_t)(e1 & 0x1FFFF) * 8 + c];
        float2 p0 = __half22float2(*(const __half2*)&r0.x);
        float2 p1 = __half22float2(*(const __half2*)&r0.y);
        float2 p2 = __half22float2(*(const __half2*)&r1.x);
        float2 p3 = __half22float2(*(const __half2*)&r1.y);
        ax += w0 * p0.x; ay += w0 * p0.y; az += w0 * p1.x; aw += w0 * p1.y;
        bx += w1 * p2.x; by += w1 * p2.y; bz += w1 * p3.x; bw += w1 * p3.y;
    }
    if (i < e) {
        int e0 = es[i];
        float w0 = (float)((unsigned)e0 >> 17) * (1.0f / 32768.0f);
        uint2 r0 = gin[(size_t)(e0 & 0x1FFFF) * 8 + c];
        float2 p0 = __half22float2(*(const __half2*)&r0.x);
        float2 p1 = __half22float2(*(const __half2*)&r0.y);
        ax += w0 * p0.x; ay += w0 * p0.y; az += w0 * p1.x; aw += w0 * p1.y;
    }
    ax += bx; ay += by; az += bz; aw += bw;
    // reduce across the 2 q-groups (xor 8 stays within each 16-lane group)
    ax += __shfl_xor(ax, 8);
    ay += __shfl_xor(ay, 8);
    az += __shfl_xor(az, 8);
    aw += __shfl_xor(aw, 8);
    float4 fav = fown[(size_t)node * 8 + c];
    float di = dinv[node];
    float fx = fav.x - ax * di;
    float fy = fav.y - ay * di;
    float fz = fav.z - az * di;
    float fw = fav.w - aw * di;
    if (MODE != 2) {
        if (q == 0) {
            float4 t; t.x = fx; t.y = fy; t.z = fz; t.w = fw;
            fwr[(size_t)node * 8 + c] = t;
            __half2 a = __float22half2_rn(make_float2(fx * di, fy * di));
            __half2 bb = __float22half2_rn(make_float2(fz * di, fw * di));
            uint2 m;
            m.x = *(unsigned*)&a;
            m.y = *(unsigned*)&bb;
            gout[(size_t)node * 8 + c] = m;
        } else {
            float4 o;
            if (MODE == 1) {
                o.x = theta0 * fav.x + theta * fx;
                o.y = theta0 * fav.y + theta * fy;
                o.z = theta0 * fav.z + theta * fz;
                o.w = theta0 * fav.w + theta * fw;
            } else {
                o = out[(size_t)node * 8 + c];
                o.x += theta * fx; o.y += theta * fy;
                o.z += theta * fz; o.w += theta * fw;
            }
            out[(size_t)node * 8 + c] = o;
        }
    } else {
        if (q == 1) {
            float4 o = out[(size_t)node * 8 + c];
            o.x += theta * fx; o.y += theta * fy;
            o.z += theta * fz; o.w += theta * fw;
            out[(size_t)node * 8 + c] = o;
        }
    }
}

// ---------------- fallback (small ws / large N): atomic scatter path ----------------

__global__ void fb_deg_kernel(const int* __restrict__ dst, const float* __restrict__ mask,
                              float* __restrict__ deg, int E) {
    int e = blockIdx.x * blockDim.x + threadIdx.x;
    if (e < E) atomicAdd(&deg[dst[e]], mask[e]);
}

__global__ void fb_dinv_kernel(float* __restrict__ deg, int N) {
    int i = blockIdx.x * blockDim.x + threadIdx.x;
    if (i < N) {
        float d = deg[i];
        d = d > 1.0f ? d : 1.0f;
        deg[i] = 1.0f / sqrtf(d);
    }
}

__global__ void fb_init_kernel(const float4* __restrict__ feat, float4* __restrict__ fbuf,
                               float4* __restrict__ out, int n4) {
    int i = blockIdx.x * blockDim.x + threadIdx.x;
    if (i < n4) {
        float4 f = feat[i];
        fbuf[i] = f;
        float4 o;
        o.x = 0.2f * f.x; o.y = 0.2f * f.y; o.z = 0.2f * f.z; o.w = 0.2f * f.w;
        out[i] = o;
    }
}

__global__ void fb_scatter_kernel(const float4* __restrict__ fbuf, const float* __restrict__ dinv,
                                  const int* __restrict__ src, const int* __restrict__ dst,
                                  const float* __restrict__ mask, float* __restrict__ agg, int E) {
    int t = blockIdx.x * blockDim.x + threadIdx.x;
    int e = t >> 3;
    if (e >= E) return;
    int c4 = t & 7;
    int s = src[e];
    int d = dst[e];
    float w = mask[e] * dinv[s];
    float4 f = fbuf[s * 8 + c4];
    float* ap = agg + (size_t)d * FDIM + c4 * 4;
    atomicAdd(ap + 0, f.x * w);
    atomicAdd(ap + 1, f.y * w);
    atomicAdd(ap + 2, f.z * w);
    atomicAdd(ap + 3, f.w * w);
}

__global__ void fb_update_kernel(float4* __restrict__ fbuf, float4* __restrict__ agg,
                                 const float* __restrict__ dinv, float4* __restrict__ out,
                                 float theta, int n4) {
    int t = blockIdx.x * blockDim.x + threadIdx.x;
    if (t >= n4) return;
    int node = t >> 3;
    float di = dinv[node];
    float4 a = agg[t];
    float4 z; z.x = 0.f; z.y = 0.f; z.z = 0.f; z.w = 0.f;
    agg[t] = z;
    float4 f = fbuf[t];
    f.x -= a.x * di; f.y -= a.y * di; f.z -= a.z * di; f.w -= a.w * di;
    fbuf[t] = f;
    float4 o = out[t];
    o.x += theta * f.x; o.y += theta * f.y; o.z += theta * f.z; o.w += theta * f.w;
    out[t] = o;
}

// ---------------- launch ----------------

static inline size_t align_up(size_t x) { return (x + 63) & ~(size_t)63; }  // 64-elem align

extern "C" void kernel_launch(void* const* d_in, const int* in_sizes, int n_in,
                              void* d_out, int out_size, void* d_ws, size_t ws_size,
                              hipStream_t stream) {
    const float* feat = (const float*)d_in[0];
    const int* src = (const int*)d_in[1];
    const int* dst = (const int*)d_in[2];
    const float* mask = (const float*)d_in[3];
    float* out = (float*)d_out;

    const int N = in_sizes[0] / FDIM;
    const int E = in_sizes[1];
    const float thetas[5] = {0.2f, -0.4f, 0.3f, -0.15f, 0.05f};
    const int B = 256;

    const int nbkt = (N + BKT_NODES - 1) / BKT_NODES;
    const int M2 = nbkt * NBLK;
    const int S = (E + NBLK - 1) / NBLK;  // edges per P1/P3 block
    const int nbM2 = (M2 + B - 1) / B;

    // ws layout (4B elements, 64-elem aligned regions).
    // Persistent: dinv, row_ptr, esI, m0, m1. Overlay region o_big:
    //   build: esp(2E), cntT(M2), obase(M2), bsums(4096)
    //   agg:   f(32N)   [f first written in round 1, after build is dead]
    size_t o_dinv = 0;                                    // N
    size_t o_rp   = align_up(o_dinv + N);                 // N+1
    size_t o_esI  = align_up(o_rp + N + 1);               // E
    size_t o_m0   = align_up(o_esI + (size_t)E);          // 16N
    size_t o_m1   = align_up(o_m0 + (size_t)N * 16);      // 16N
    size_t o_big  = align_up(o_m1 + (size_t)N * 16);
    size_t o_esp  = o_big;                                // 2E
    size_t o_cntT = align_up(o_esp + 2 * (size_t)E);      // M2
    size_t o_ob   = align_up(o_cntT + (size_t)M2);        // M2
    size_t o_bs   = align_up(o_ob + (size_t)M2);          // 4096
    size_t build_end = o_bs + 4096;
    size_t o_f    = o_big;                                // 32N
    size_t agg_end = o_f + (size_t)N * FDIM;
    size_t need = (build_end > agg_end ? build_end : agg_end) * 4;

    float* wsf = (float*)d_ws;
    int* wsi = (int*)d_ws;

    int nbE = (E + B - 1) / B;
    int nbN = (N + B - 1) / B;

    if (ws_size >= need && N <= (1 << 17) && nbkt <= MAXBKT && nbM2 <= 4096) {
        float* dinv = wsf + o_dinv;
        int* row_ptr = wsi + o_rp;
        int* esI = wsi + o_esI;
        uint2* m0 = (uint2*)(wsi + o_m0);
        uint2* m1 = (uint2*)(wsi + o_m1);
        int2* esp = (int2*)(wsi + o_esp);
        int* cntT = wsi + o_cntT;
        int* obase = wsi + o_ob;
        int* bsums = wsi + o_bs;
        float4* f = (float4*)(wsf + o_f);

        p1_kernel<<<NBLK, B, 0, stream>>>(dst, cntT, nbkt, S, E);
        scanA_kernel<<<nbM2, B, 0, stream>>>(cntT, obase, bsums, M2);
        scan2_kernel<<<1, 512, 0, stream>>>(bsums, nbM2);
        scanC_kernel<<<nbM2, B, 0, stream>>>(obase, bsums, M2);
        p3_kernel<<<NBLK, B, 0, stream>>>(src, dst, mask, obase, esp, S, E);
        p4_kernel<<<nbkt, 512, 0, stream>>>(esp, obase, esI, row_ptr, dinv,
                                            (const float4*)feat, m0, nbkt, N, E);

        int aggWaves = (N + 3) / 4;
        int agg_blocks = (aggWaves * 64 + B - 1) / B;
        // r1: own=feat, chain->f, gather m0 -> write m1, out = th0*feat + th1*f1
        aggregate_kernel<1><<<agg_blocks, B, 0, stream>>>((const float4*)feat, f, m0, m1,
                                                          (float4*)out, row_ptr, esI, dinv,
                                                          thetas[1], thetas[0], N);
        // r2: own=f in-place, gather m1 -> write m0
        aggregate_kernel<0><<<agg_blocks, B, 0, stream>>>(f, f, m1, m0, (float4*)out,
                                                          row_ptr, esI, dinv, thetas[2], 0.f, N);
        // r3: own=f in-place, gather m0 -> write m1
        aggregate_kernel<0><<<agg_blocks, B, 0, stream>>>(f, f, m0, m1, (float4*)out,
                                                          row_ptr, esI, dinv, thetas[3], 0.f, N);
        // r4: own=f, gather m1, out only
        aggregate_kernel<2><<<agg_blocks, B, 0, stream>>>(f, f, m1, m0, (float4*)out,
                                                          row_ptr, esI, dinv, thetas[4], 0.f, N);
    } else {
        // fallback: atomic-scatter path
        float* deg = wsf;                       // N
        float* agg = deg + align_up(N);         // 32N
        float* fbuf = agg + (size_t)N * FDIM;   // 32N

        hipMemsetAsync(d_ws, 0, (align_up(N) + (size_t)N * FDIM) * 4, stream);
        fb_deg_kernel<<<nbE, B, 0, stream>>>(dst, mask, deg, E);
        fb_dinv_kernel<<<nbN, B, 0, stream>>>(deg, N);

        int n4 = N * (FDIM / 4);
        fb_init_kernel<<<(n4 + B - 1) / B, B, 0, stream>>>((const float4*)feat, (float4*)fbuf,
                                                           (float4*)out, n4);
        long long sc_threads = (long long)E * 8;
        int sc_blocks = (int)((sc_threads + B - 1) / B);
        for (int k = 1; k < 5; ++k) {
            fb_scatter_kernel<<<sc_blocks, B, 0, stream>>>((const float4*)fbuf, deg, src, dst,
                                                           mask, agg, E);
            fb_update_kernel<<<(n4 + B - 1) / B, B, 0, stream>>>((float4*)fbuf, (float4*)agg,
                                                                 deg, (float4*)out, thetas[k], n4);
        }
    }
}

// Round 12
// 193.332 us; speedup vs baseline: 14.0877x; 1.0049x over previous
//
#include <hip/hip_runtime.h>
#include <hip/hip_fp16.h>

// PolyConv via CSR-gather. Build = block-local LDS counting sort:
//   p3: each block stages its 1536-edge slice in LDS, histograms buckets
//       (g=dst>>8), LDS-scans, writes esp grouped-by-bucket WITHIN its own
//       contiguous slice (streaming writes), and emits lofsT[g][b].
//   scanR: R[g] = sum_b lofsT[g][b]  (coalesced row sums; R = esI segment base)
//   p4: per bucket: walk per-block sub-segments, LDS count/deg -> row_ptr +
//       dinv, LDS rank -> packed esI {src:17|q15(mask):15}, fused fp16 mirror.
// Rounds: 4x aggregate, 4 nodes/wave, fp16 gather mirror pre-scaled by
// dinv[src] (ping-pong m0/m1), in-place fp32 chain.
// feat [N,32] f32, src [E] i32, dst [E] i32, mask [E] f32 -> h [N,32] f32.

#define FDIM 32
#define DLO_BITS 8
#define BKT_NODES 256          // nodes per bucket = 1<<DLO_BITS
#define S_FIX 1536             // edges per p3 block (3 x 512)
#define MAXBKT 512             // supports N <= 131072 (src fits 17 bits)

// ---------------- build ----------------

// p3: block-local counting sort of a 1536-edge slice.
__global__ __launch_bounds__(512) void p3_kernel(const int* __restrict__ src,
                                                 const int* __restrict__ dst,
                                                 const float* __restrict__ mask,
                                                 int* __restrict__ lofsT,
                                                 int2* __restrict__ esp,
                                                 int NBLKp, int nbkt, int E) {
    __shared__ int sdst[S_FIX];
    __shared__ int ssrc[S_FIX];
    __shared__ float smask[S_FIX];
    __shared__ int lh[MAXBKT];
    __shared__ int ws[8];
    int b = blockIdx.x;
    int tid = threadIdx.x;
    int e0 = b * S_FIX;
    int n = E - e0;
    if (n > S_FIX) n = S_FIX;
    if (n < 0) n = 0;
    for (int t = tid; t < n; t += 512) {
        sdst[t] = dst[e0 + t];
        ssrc[t] = src[e0 + t];
        smask[t] = mask[e0 + t];
    }
    lh[tid] = 0;  // blockDim == MAXBKT == 512
    __syncthreads();
    for (int t = tid; t < n; t += 512) atomicAdd(&lh[sdst[t] >> DLO_BITS], 1);
    __syncthreads();
    // exclusive scan of lh[512]
    int v = lh[tid];
    int lane = tid & 63, wv = tid >> 6;
    int x = v;
#pragma unroll
    for (int o = 1; o < 64; o <<= 1) {
        int y = __shfl_up(x, o);
        if (lane >= o) x += y;
    }
    if (lane == 63) ws[wv] = x;
    __syncthreads();
    int add = 0;
    for (int i = 0; i < wv; ++i) add += ws[i];
    x += add;
    int excl = x - v;
    lh[tid] = excl;  // own slot only
    if (tid < nbkt) lofsT[(size_t)tid * NBLKp + b] = excl;
    if (tid == 0) lofsT[(size_t)nbkt * NBLKp + b] = n;
    __syncthreads();
    // scatter into own contiguous slice, grouped by bucket (streaming window)
    for (int t = tid; t < n; t += 512) {
        int d = sdst[t];
        int g = d >> DLO_BITS;
        int pos = e0 + atomicAdd(&lh[g], 1);
        int2 vv;
        vv.x = ssrc[t] | ((d & (BKT_NODES - 1)) << 17);
        vv.y = __float_as_int(smask[t]);
        esp[pos] = vv;
    }
}

// R[g] = sum_b lofsT[g*NBLKp + b], g in [0, nbkt]. R[g] = esI base of bucket g.
__global__ void scanR_kernel(const int* __restrict__ lofsT, int* __restrict__ R, int NBLKp) {
    int g = blockIdx.x;
    int tid = threadIdx.x;  // 256
    int s = 0;
    for (int t = tid; t < NBLKp; t += 256) s += lofsT[(size_t)g * NBLKp + t];
#pragma unroll
    for (int o = 1; o < 64; o <<= 1) s += __shfl_xor(s, o);
    __shared__ int wsum[4];
    int lane = tid & 63, wv = tid >> 6;
    if (lane == 0) wsum[wv] = s;
    __syncthreads();
    if (tid == 0) R[g] = wsum[0] + wsum[1] + wsum[2] + wsum[3];
}

// p4: one 512-thread block per bucket. Walks per-block sub-segments of esp,
// LDS count+deg -> scan -> row_ptr + dinv, LDS rank -> packed esI, fused
// fp16 mirror init m0 = fp16(feat * dinv).
__global__ __launch_bounds__(512) void p4_kernel(const int2* __restrict__ esp,
                                                 const int* __restrict__ lofsT,
                                                 const int* __restrict__ R,
                                                 int* __restrict__ esI,
                                                 int* __restrict__ row_ptr,
                                                 float* __restrict__ dinv,
                                                 const float4* __restrict__ feat,
                                                 uint2* __restrict__ m0,
                                                 int NBLKp, int nbkt, int N, int E) {
    __shared__ int lcnt[BKT_NODES];
    __shared__ int lofs[BKT_NODES];
    __shared__ float ldeg[BKT_NODES];
    __shared__ int ws[8];
    int g = blockIdx.x;
    int tid = threadIdx.x;
    if (tid < BKT_NODES) { lcnt[tid] = 0; ldeg[tid] = 0.0f; }
    __syncthreads();
    int segbase = R[g];
    // pass A: count + degree
    for (int b = tid; b < NBLKp; b += 512) {
        int st = lofsT[(size_t)g * NBLKp + b];
        int en = lofsT[(size_t)(g + 1) * NBLKp + b];
        int base = b * S_FIX;
        for (int i = st; i < en; ++i) {
            int2 v = esp[base + i];
            int dlo = v.x >> 17;
            atomicAdd(&lcnt[dlo], 1);
            atomicAdd(&ldeg[dlo], __int_as_float(v.y));
        }
    }
    __syncthreads();
    // 512-wide exclusive scan, zero-padded past BKT_NODES
    int v = (tid < BKT_NODES) ? lcnt[tid] : 0;
    int lane = tid & 63, wv = tid >> 6;
    int x = v;
#pragma unroll
    for (int o = 1; o < 64; o <<= 1) {
        int y = __shfl_up(x, o);
        if (lane >= o) x += y;
    }
    if (lane == 63) ws[wv] = x;
    __syncthreads();
    int add = 0;
    for (int i = 0; i < wv; ++i) add += ws[i];
    x += add;
    int excl = x - v;
    if (tid < BKT_NODES) {
        lofs[tid] = excl;
        int node = g * BKT_NODES + tid;
        if (node < N) {
            row_ptr[node] = segbase + excl;
            float d = ldeg[tid];
            d = d > 1.0f ? d : 1.0f;
            float di = 1.0f / sqrtf(d);  // precise: reused across 4 rounds
            dinv[node] = di;
            ldeg[tid] = di;  // ldeg now holds dinv (own slot; synced below)
        }
    }
    if (g == 0 && tid == 0) row_ptr[N] = E;
    __syncthreads();
    if (tid < BKT_NODES) lcnt[tid] = 0;  // reuse as rank counters
    __syncthreads();
    // pass B: rank + packed scatter (bucket-local 32KB window)
    for (int b = tid; b < NBLKp; b += 512) {
        int st = lofsT[(size_t)g * NBLKp + b];
        int en = lofsT[(size_t)(g + 1) * NBLKp + b];
        int base = b * S_FIX;
        for (int i = st; i < en; ++i) {
            int2 v2 = esp[base + i];
            int dlo = v2.x >> 17;
            int r = atomicAdd(&lcnt[dlo], 1);
            float mk = __int_as_float(v2.y);
            int wq = (int)(mk * 32768.0f + 0.5f);
            if (wq > 32767) wq = 32767;
            esI[segbase + lofs[dlo] + r] = (v2.x & 0x1FFFF) | (wq << 17);
        }
    }
    // fused mirror init (ldeg holds dinv; written before the pre-pass-B sync)
    int base_node = g * BKT_NODES;
    for (int t = tid; t < BKT_NODES * 8; t += 512) {
        int nl = t >> 3;
        int n2 = base_node + nl;
        if (n2 >= N) break;
        float di = ldeg[nl];
        float4 f = feat[(size_t)n2 * 8 + (t & 7)];
        __half2 a = __float22half2_rn(make_float2(f.x * di, f.y * di));
        __half2 bb = __float22half2_rn(make_float2(f.z * di, f.w * di));
        uint2 m;
        m.x = *(unsigned*)&a;
        m.y = *(unsigned*)&bb;
        m0[(size_t)n2 * 8 + (t & 7)] = m;
    }
}

// ---------------- aggregate (unchanged from R11) ----------------
// 4 nodes per wave; 16 lanes per node. c = lane&7 (uint2 chunk of the 64B
// fp16 row), q = (lane>>3)&1 (2-way edge parallel, 2-deep unroll).
template <int MODE>
__global__ __launch_bounds__(256) void aggregate_kernel(
    const float4* __restrict__ fown, float4* __restrict__ fwr,
    const uint2* __restrict__ gin, uint2* __restrict__ gout,
    float4* __restrict__ out,
    const int* __restrict__ row_ptr, const int* __restrict__ es,
    const float* __restrict__ dinv, float theta, float theta0, int N) {
    int wave = (blockIdx.x * blockDim.x + threadIdx.x) >> 6;
    int lane = threadIdx.x & 63;
    int node = wave * 4 + (lane >> 4);
    if (node >= N) return;
    int l16 = lane & 15;
    int c = l16 & 7;
    int q = l16 >> 3;  // 0..1
    int b = row_ptr[node];
    int e = row_ptr[node + 1];
    float ax = 0.f, ay = 0.f, az = 0.f, aw = 0.f;
    float bx = 0.f, by = 0.f, bz = 0.f, bw = 0.f;
    int i = b + q;
    for (; i + 2 < e; i += 4) {
        int e0 = es[i];
        int e1 = es[i + 2];
        float w0 = (float)((unsigned)e0 >> 17) * (1.0f / 32768.0f);
        float w1 = (float)((unsigned)e1 >> 17) * (1.0f / 32768.0f);
        uint2 r0 = gin[(size_t)(e0 & 0x1FFFF) * 8 + c];
        uint2 r1 = gin[(size_t)(e1 & 0x1FFFF) * 8 + c];
        float2 p0 = __half22float2(*(const __half2*)&r0.x);
        float2 p1 = __half22float2(*(const __half2*)&r0.y);
        float2 p2 = __half22float2(*(const __half2*)&r1.x);
        float2 p3 = __half22float2(*(const __half2*)&r1.y);
        ax += w0 * p0.x; ay += w0 * p0.y; az += w0 * p1.x; aw += w0 * p1.y;
        bx += w1 * p2.x; by += w1 * p2.y; bz += w1 * p3.x; bw += w1 * p3.y;
    }
    if (i < e) {
        int e0 = es[i];
        float w0 = (float)((unsigned)e0 >> 17) * (1.0f / 32768.0f);
        uint2 r0 = gin[(size_t)(e0 & 0x1FFFF) * 8 + c];
        float2 p0 = __half22float2(*(const __half2*)&r0.x);
        float2 p1 = __half22float2(*(const __half2*)&r0.y);
        ax += w0 * p0.x; ay += w0 * p0.y; az += w0 * p1.x; aw += w0 * p1.y;
    }
    ax += bx; ay += by; az += bz; aw += bw;
    ax += __shfl_xor(ax, 8);
    ay += __shfl_xor(ay, 8);
    az += __shfl_xor(az, 8);
    aw += __shfl_xor(aw, 8);
    float4 fav = fown[(size_t)node * 8 + c];
    float di = dinv[node];
    float fx = fav.x - ax * di;
    float fy = fav.y - ay * di;
    float fz = fav.z - az * di;
    float fw = fav.w - aw * di;
    if (MODE != 2) {
        if (q == 0) {
            float4 t; t.x = fx; t.y = fy; t.z = fz; t.w = fw;
            fwr[(size_t)node * 8 + c] = t;
            __half2 a = __float22half2_rn(make_float2(fx * di, fy * di));
            __half2 bb = __float22half2_rn(make_float2(fz * di, fw * di));
            uint2 m;
            m.x = *(unsigned*)&a;
            m.y = *(unsigned*)&bb;
            gout[(size_t)node * 8 + c] = m;
        } else {
            float4 o;
            if (MODE == 1) {
                o.x = theta0 * fav.x + theta * fx;
                o.y = theta0 * fav.y + theta * fy;
                o.z = theta0 * fav.z + theta * fz;
                o.w = theta0 * fav.w + theta * fw;
            } else {
                o = out[(size_t)node * 8 + c];
                o.x += theta * fx; o.y += theta * fy;
                o.z += theta * fz; o.w += theta * fw;
            }
            out[(size_t)node * 8 + c] = o;
        }
    } else {
        if (q == 1) {
            float4 o = out[(size_t)node * 8 + c];
            o.x += theta * fx; o.y += theta * fy;
            o.z += theta * fz; o.w += theta * fw;
            out[(size_t)node * 8 + c] = o;
        }
    }
}

// ---------------- fallback (small ws / large N): atomic scatter path ----------------

__global__ void fb_deg_kernel(const int* __restrict__ dst, const float* __restrict__ mask,
                              float* __restrict__ deg, int E) {
    int e = blockIdx.x * blockDim.x + threadIdx.x;
    if (e < E) atomicAdd(&deg[dst[e]], mask[e]);
}

__global__ void fb_dinv_kernel(float* __restrict__ deg, int N) {
    int i = blockIdx.x * blockDim.x + threadIdx.x;
    if (i < N) {
        float d = deg[i];
        d = d > 1.0f ? d : 1.0f;
        deg[i] = 1.0f / sqrtf(d);
    }
}

__global__ void fb_init_kernel(const float4* __restrict__ feat, float4* __restrict__ fbuf,
                               float4* __restrict__ out, int n4) {
    int i = blockIdx.x * blockDim.x + threadIdx.x;
    if (i < n4) {
        float4 f = feat[i];
        fbuf[i] = f;
        float4 o;
        o.x = 0.2f * f.x; o.y = 0.2f * f.y; o.z = 0.2f * f.z; o.w = 0.2f * f.w;
        out[i] = o;
    }
}

__global__ void fb_scatter_kernel(const float4* __restrict__ fbuf, const float* __restrict__ dinv,
                                  const int* __restrict__ src, const int* __restrict__ dst,
                                  const float* __restrict__ mask, float* __restrict__ agg, int E) {
    int t = blockIdx.x * blockDim.x + threadIdx.x;
    int e = t >> 3;
    if (e >= E) return;
    int c4 = t & 7;
    int s = src[e];
    int d = dst[e];
    float w = mask[e] * dinv[s];
    float4 f = fbuf[s * 8 + c4];
    float* ap = agg + (size_t)d * FDIM + c4 * 4;
    atomicAdd(ap + 0, f.x * w);
    atomicAdd(ap + 1, f.y * w);
    atomicAdd(ap + 2, f.z * w);
    atomicAdd(ap + 3, f.w * w);
}

__global__ void fb_update_kernel(float4* __restrict__ fbuf, float4* __restrict__ agg,
                                 const float* __restrict__ dinv, float4* __restrict__ out,
                                 float theta, int n4) {
    int t = blockIdx.x * blockDim.x + threadIdx.x;
    if (t >= n4) return;
    int node = t >> 3;
    float di = dinv[node];
    float4 a = agg[t];
    float4 z; z.x = 0.f; z.y = 0.f; z.z = 0.f; z.w = 0.f;
    agg[t] = z;
    float4 f = fbuf[t];
    f.x -= a.x * di; f.y -= a.y * di; f.z -= a.z * di; f.w -= a.w * di;
    fbuf[t] = f;
    float4 o = out[t];
    o.x += theta * f.x; o.y += theta * f.y; o.z += theta * f.z; o.w += theta * f.w;
    out[t] = o;
}

// ---------------- launch ----------------

static inline size_t align_up(size_t x) { return (x + 63) & ~(size_t)63; }  // 64-elem align

extern "C" void kernel_launch(void* const* d_in, const int* in_sizes, int n_in,
                              void* d_out, int out_size, void* d_ws, size_t ws_size,
                              hipStream_t stream) {
    const float* feat = (const float*)d_in[0];
    const int* src = (const int*)d_in[1];
    const int* dst = (const int*)d_in[2];
    const float* mask = (const float*)d_in[3];
    float* out = (float*)d_out;

    const int N = in_sizes[0] / FDIM;
    const int E = in_sizes[1];
    const float thetas[5] = {0.2f, -0.4f, 0.3f, -0.15f, 0.05f};
    const int B = 256;

    const int nbkt = (N + BKT_NODES - 1) / BKT_NODES;
    const int NBLKp = (E + S_FIX - 1) / S_FIX;

    // ws layout (4B elements, 64-elem aligned) — ALL PERSISTENT (no overlay;
    // ~47MB total, ws is much larger; R9 lesson: overlays invite aliasing bugs).
    size_t o_dinv = 0;                                            // N
    size_t o_rp    = align_up(o_dinv + N);                        // N+1
    size_t o_esI   = align_up(o_rp + N + 1);                      // E
    size_t o_m0    = align_up(o_esI + (size_t)E);                 // 16N
    size_t o_m1    = align_up(o_m0 + (size_t)N * 16);             // 16N
    size_t o_esp   = align_up(o_m1 + (size_t)N * 16);             // 2E
    size_t o_lofsT = align_up(o_esp + 2 * (size_t)E);             // (nbkt+1)*NBLKp
    size_t o_R     = align_up(o_lofsT + (size_t)(nbkt + 1) * NBLKp);  // nbkt+1
    size_t o_f     = align_up(o_R + nbkt + 1);                    // 32N
    size_t need = (o_f + (size_t)N * FDIM) * 4;

    float* wsf = (float*)d_ws;
    int* wsi = (int*)d_ws;

    int nbE = (E + B - 1) / B;
    int nbN = (N + B - 1) / B;

    if (ws_size >= need && N <= (1 << 17) && nbkt <= MAXBKT) {
        float* dinv = wsf + o_dinv;
        int* row_ptr = wsi + o_rp;
        int* esI = wsi + o_esI;
        uint2* m0 = (uint2*)(wsi + o_m0);
        uint2* m1 = (uint2*)(wsi + o_m1);
        int2* esp = (int2*)(wsi + o_esp);
        int* lofsT = wsi + o_lofsT;
        int* R = wsi + o_R;
        float4* f = (float4*)(wsf + o_f);

        p3_kernel<<<NBLKp, 512, 0, stream>>>(src, dst, mask, lofsT, esp, NBLKp, nbkt, E);
        scanR_kernel<<<nbkt + 1, 256, 0, stream>>>(lofsT, R, NBLKp);
        p4_kernel<<<nbkt, 512, 0, stream>>>(esp, lofsT, R, esI, row_ptr, dinv,
                                            (const float4*)feat, m0, NBLKp, nbkt, N, E);

        int aggWaves = (N + 3) / 4;
        int agg_blocks = (aggWaves * 64 + B - 1) / B;
        // r1: own=feat, chain->f, gather m0 -> write m1, out = th0*feat + th1*f1
        aggregate_kernel<1><<<agg_blocks, B, 0, stream>>>((const float4*)feat, f, m0, m1,
                                                          (float4*)out, row_ptr, esI, dinv,
                                                          thetas[1], thetas[0], N);
        // r2: own=f in-place, gather m1 -> write m0
        aggregate_kernel<0><<<agg_blocks, B, 0, stream>>>(f, f, m1, m0, (float4*)out,
                                                          row_ptr, esI, dinv, thetas[2], 0.f, N);
        // r3: own=f in-place, gather m0 -> write m1
        aggregate_kernel<0><<<agg_blocks, B, 0, stream>>>(f, f, m0, m1, (float4*)out,
                                                          row_ptr, esI, dinv, thetas[3], 0.f, N);
        // r4: own=f, gather m1, out only
        aggregate_kernel<2><<<agg_blocks, B, 0, stream>>>(f, f, m1, m0, (float4*)out,
                                                          row_ptr, esI, dinv, thetas[4], 0.f, N);
    } else {
        // fallback: atomic-scatter path
        float* deg = wsf;                       // N
        float* agg = deg + align_up(N);         // 32N
        float* fbuf = agg + (size_t)N * FDIM;   // 32N

        hipMemsetAsync(d_ws, 0, (align_up(N) + (size_t)N * FDIM) * 4, stream);
        fb_deg_kernel<<<nbE, B, 0, stream>>>(dst, mask, deg, E);
        fb_dinv_kernel<<<nbN, B, 0, stream>>>(deg, N);

        int n4 = N * (FDIM / 4);
        fb_init_kernel<<<(n4 + B - 1) / B, B, 0, stream>>>((const float4*)feat, (float4*)fbuf,
                                                           (float4*)out, n4);
        long long sc_threads = (long long)E * 8;
        int sc_blocks = (int)((sc_threads + B - 1) / B);
        for (int k = 1; k < 5; ++k) {
            fb_scatter_kernel<<<sc_blocks, B, 0, stream>>>((const float4*)fbuf, deg, src, dst,
                                                           mask, agg, E);
            fb_update_kernel<<<(n4 + B - 1) / B, B, 0, stream>>>((float4*)fbuf, (float4*)agg,
                                                                 deg, (float4*)out, thetas[k], n4);
        }
    }
}

// Round 13
// 174.903 us; speedup vs baseline: 15.5721x; 1.1054x over previous
//
#include <hip/hip_runtime.h>
#include <hip/hip_fp16.h>

// PolyConv via CSR-gather. Build = block-local LDS counting sort:
//   p3: block sorts its 1536-edge slice by bucket (g=dst>>8) into its own
//       contiguous esp window (streaming), emits lofsT[g][b].
//   scanR: R[g] = sum_b lofsT[g][b]  (= esI segment base of bucket g)
//   p4: per bucket: block-scan per-(g,b) counts -> staging positions, ONE
//       scattered pass over esp staging the bucket into LDS (+count/deg),
//       LDS scan -> row_ptr+dinv, linear LDS pass -> packed esI, fused fp16
//       mirror m0 = fp16(feat*dinv).
// Rounds: 4x aggregate, 4 nodes/wave, fp16 gather mirror pre-scaled by
// dinv[src] (ping-pong m0/m1), in-place fp32 chain.
// feat [N,32] f32, src [E] i32, dst [E] i32, mask [E] f32 -> h [N,32] f32.

#define FDIM 32
#define DLO_BITS 8
#define BKT_NODES 256          // nodes per bucket = 1<<DLO_BITS
#define S_FIX 1536             // edges per p3 block (3 x 512)
#define MAXBKT 512             // supports N <= 131072 (src fits 17 bits)
#define MAXNBLK 2048           // p4 pseg capacity (E <= 3.1M)
#define PCAP 5120              // staged edges per bucket (mean 4092 + 16 sigma)

// ---------------- build ----------------

// p3: block-local counting sort of a 1536-edge slice (unchanged from R12).
__global__ __launch_bounds__(512) void p3_kernel(const int* __restrict__ src,
                                                 const int* __restrict__ dst,
                                                 const float* __restrict__ mask,
                                                 int* __restrict__ lofsT,
                                                 int2* __restrict__ esp,
                                                 int NBLKp, int nbkt, int E) {
    __shared__ int sdst[S_FIX];
    __shared__ int ssrc[S_FIX];
    __shared__ float smask[S_FIX];
    __shared__ int lh[MAXBKT];
    __shared__ int ws[8];
    int b = blockIdx.x;
    int tid = threadIdx.x;
    int e0 = b * S_FIX;
    int n = E - e0;
    if (n > S_FIX) n = S_FIX;
    if (n < 0) n = 0;
    for (int t = tid; t < n; t += 512) {
        sdst[t] = dst[e0 + t];
        ssrc[t] = src[e0 + t];
        smask[t] = mask[e0 + t];
    }
    lh[tid] = 0;  // blockDim == MAXBKT == 512
    __syncthreads();
    for (int t = tid; t < n; t += 512) atomicAdd(&lh[sdst[t] >> DLO_BITS], 1);
    __syncthreads();
    int v = lh[tid];
    int lane = tid & 63, wv = tid >> 6;
    int x = v;
#pragma unroll
    for (int o = 1; o < 64; o <<= 1) {
        int y = __shfl_up(x, o);
        if (lane >= o) x += y;
    }
    if (lane == 63) ws[wv] = x;
    __syncthreads();
    int add = 0;
    for (int i = 0; i < wv; ++i) add += ws[i];
    x += add;
    int excl = x - v;
    lh[tid] = excl;
    if (tid < nbkt) lofsT[(size_t)tid * NBLKp + b] = excl;
    if (tid == 0) lofsT[(size_t)nbkt * NBLKp + b] = n;
    __syncthreads();
    for (int t = tid; t < n; t += 512) {
        int d = sdst[t];
        int g = d >> DLO_BITS;
        int pos = e0 + atomicAdd(&lh[g], 1);
        int2 vv;
        vv.x = ssrc[t] | ((d & (BKT_NODES - 1)) << 17);
        vv.y = __float_as_int(smask[t]);
        esp[pos] = vv;
    }
}

// R[g] = sum_b lofsT[g*NBLKp + b]
__global__ void scanR_kernel(const int* __restrict__ lofsT, int* __restrict__ R, int NBLKp) {
    int g = blockIdx.x;
    int tid = threadIdx.x;  // 256
    int s = 0;
    for (int t = tid; t < NBLKp; t += 256) s += lofsT[(size_t)g * NBLKp + t];
#pragma unroll
    for (int o = 1; o < 64; o <<= 1) s += __shfl_xor(s, o);
    __shared__ int wsum[4];
    int lane = tid & 63, wv = tid >> 6;
    if (lane == 0) wsum[wv] = s;
    __syncthreads();
    if (tid == 0) R[g] = wsum[0] + wsum[1] + wsum[2] + wsum[3];
}

// p4: one 512-thread block per bucket. LDS-staged single scattered pass.
__global__ __launch_bounds__(512) void p4_kernel(const int2* __restrict__ esp,
                                                 const int* __restrict__ lofsT,
                                                 const int* __restrict__ R,
                                                 int* __restrict__ esI,
                                                 int* __restrict__ row_ptr,
                                                 float* __restrict__ dinv,
                                                 const float4* __restrict__ feat,
                                                 uint2* __restrict__ m0,
                                                 int NBLKp, int nbkt, int N, int E) {
    __shared__ int2 sstage[PCAP];      // 40KB
    __shared__ int pseg[MAXNBLK];      // 8KB: per-(g,b) staging base
    __shared__ int lcnt[BKT_NODES];
    __shared__ int lofs[BKT_NODES];
    __shared__ float ldeg[BKT_NODES];
    __shared__ int ws[8];
    __shared__ int carry;
    int g = blockIdx.x;
    int tid = threadIdx.x;
    int lane = tid & 63, wv = tid >> 6;
    if (tid < BKT_NODES) { lcnt[tid] = 0; ldeg[tid] = 0.0f; }
    if (tid == 0) carry = 0;
    __syncthreads();
    int segbase = R[g];
    // block-exclusive-scan of per-(g,b) counts -> pseg, total T in carry
    for (int base = 0; base < NBLKp; base += 512) {
        int b = base + tid;
        int c = 0;
        if (b < NBLKp)
            c = lofsT[(size_t)(g + 1) * NBLKp + b] - lofsT[(size_t)g * NBLKp + b];
        int x = c;
#pragma unroll
        for (int o = 1; o < 64; o <<= 1) {
            int y = __shfl_up(x, o);
            if (lane >= o) x += y;
        }
        if (lane == 63) ws[wv] = x;
        __syncthreads();
        int add = 0;
        for (int i = 0; i < wv; ++i) add += ws[i];
        x += add;
        int cc = carry;
        if (b < NBLKp) pseg[b] = x - c + cc;
        __syncthreads();
        if (tid == 511) carry = cc + x;
        __syncthreads();
    }
    int T = carry;
    bool staged = (T <= PCAP);
    // pass A: scattered read of esp (ONCE) -> stage + count + deg.
    // 4-lane groups per (g,b) sub-segment.
    int grp = tid >> 2, l4 = tid & 3;
    for (int b = grp; b < NBLKp; b += 128) {
        int st = lofsT[(size_t)g * NBLKp + b];
        int en = lofsT[(size_t)(g + 1) * NBLKp + b];
        int base = b * S_FIX;
        int pb = pseg[b];
        for (int i = st + l4; i < en; i += 4) {
            int2 v = esp[base + i];
            int dlo = v.x >> 17;
            atomicAdd(&lcnt[dlo], 1);
            atomicAdd(&ldeg[dlo], __int_as_float(v.y));
            if (staged) sstage[pb + (i - st)] = v;
        }
    }
    __syncthreads();
    // 512-wide exclusive scan of lcnt (zero-padded)
    int v = (tid < BKT_NODES) ? lcnt[tid] : 0;
    int x = v;
#pragma unroll
    for (int o = 1; o < 64; o <<= 1) {
        int y = __shfl_up(x, o);
        if (lane >= o) x += y;
    }
    if (lane == 63) ws[wv] = x;
    __syncthreads();
    int add = 0;
    for (int i = 0; i < wv; ++i) add += ws[i];
    x += add;
    int excl = x - v;
    if (tid < BKT_NODES) {
        lofs[tid] = excl;
        int node = g * BKT_NODES + tid;
        if (node < N) {
            row_ptr[node] = segbase + excl;
            float d = ldeg[tid];
            d = d > 1.0f ? d : 1.0f;
            float di = 1.0f / sqrtf(d);  // precise: reused across 4 rounds
            dinv[node] = di;
            ldeg[tid] = di;  // ldeg now holds dinv
        }
    }
    if (g == 0 && tid == 0) row_ptr[N] = E;
    __syncthreads();
    if (tid < BKT_NODES) lcnt[tid] = 0;  // reuse as rank counters
    __syncthreads();
    // pass B: rank + packed esI scatter
    if (staged) {
        for (int k = tid; k < T; k += 512) {
            int2 v2 = sstage[k];
            int dlo = v2.x >> 17;
            int r = atomicAdd(&lcnt[dlo], 1);
            float mk = __int_as_float(v2.y);
            int wq = (int)(mk * 32768.0f + 0.5f);
            if (wq > 32767) wq = 32767;
            esI[segbase + lofs[dlo] + r] = (v2.x & 0x1FFFF) | (wq << 17);
        }
    } else {
        for (int b = grp; b < NBLKp; b += 128) {
            int st = lofsT[(size_t)g * NBLKp + b];
            int en = lofsT[(size_t)(g + 1) * NBLKp + b];
            int base = b * S_FIX;
            for (int i = st + l4; i < en; i += 4) {
                int2 v2 = esp[base + i];
                int dlo = v2.x >> 17;
                int r = atomicAdd(&lcnt[dlo], 1);
                float mk = __int_as_float(v2.y);
                int wq = (int)(mk * 32768.0f + 0.5f);
                if (wq > 32767) wq = 32767;
                esI[segbase + lofs[dlo] + r] = (v2.x & 0x1FFFF) | (wq << 17);
            }
        }
    }
    // fused mirror init (ldeg holds dinv)
    int base_node = g * BKT_NODES;
    for (int t = tid; t < BKT_NODES * 8; t += 512) {
        int nl = t >> 3;
        int n2 = base_node + nl;
        if (n2 >= N) break;
        float di = ldeg[nl];
        float4 f = feat[(size_t)n2 * 8 + (t & 7)];
        __half2 a = __float22half2_rn(make_float2(f.x * di, f.y * di));
        __half2 bb = __float22half2_rn(make_float2(f.z * di, f.w * di));
        uint2 m;
        m.x = *(unsigned*)&a;
        m.y = *(unsigned*)&bb;
        m0[(size_t)n2 * 8 + (t & 7)] = m;
    }
}

// ---------------- aggregate (unchanged) ----------------
template <int MODE>
__global__ __launch_bounds__(256) void aggregate_kernel(
    const float4* __restrict__ fown, float4* __restrict__ fwr,
    const uint2* __restrict__ gin, uint2* __restrict__ gout,
    float4* __restrict__ out,
    const int* __restrict__ row_ptr, const int* __restrict__ es,
    const float* __restrict__ dinv, float theta, float theta0, int N) {
    int wave = (blockIdx.x * blockDim.x + threadIdx.x) >> 6;
    int lane = threadIdx.x & 63;
    int node = wave * 4 + (lane >> 4);
    if (node >= N) return;
    int l16 = lane & 15;
    int c = l16 & 7;
    int q = l16 >> 3;  // 0..1
    int b = row_ptr[node];
    int e = row_ptr[node + 1];
    float ax = 0.f, ay = 0.f, az = 0.f, aw = 0.f;
    float bx = 0.f, by = 0.f, bz = 0.f, bw = 0.f;
    int i = b + q;
    for (; i + 2 < e; i += 4) {
        int e0 = es[i];
        int e1 = es[i + 2];
        float w0 = (float)((unsigned)e0 >> 17) * (1.0f / 32768.0f);
        float w1 = (float)((unsigned)e1 >> 17) * (1.0f / 32768.0f);
        uint2 r0 = gin[(size_t)(e0 & 0x1FFFF) * 8 + c];
        uint2 r1 = gin[(size_t)(e1 & 0x1FFFF) * 8 + c];
        float2 p0 = __half22float2(*(const __half2*)&r0.x);
        float2 p1 = __half22float2(*(const __half2*)&r0.y);
        float2 p2 = __half22float2(*(const __half2*)&r1.x);
        float2 p3 = __half22float2(*(const __half2*)&r1.y);
        ax += w0 * p0.x; ay += w0 * p0.y; az += w0 * p1.x; aw += w0 * p1.y;
        bx += w1 * p2.x; by += w1 * p2.y; bz += w1 * p3.x; bw += w1 * p3.y;
    }
    if (i < e) {
        int e0 = es[i];
        float w0 = (float)((unsigned)e0 >> 17) * (1.0f / 32768.0f);
        uint2 r0 = gin[(size_t)(e0 & 0x1FFFF) * 8 + c];
        float2 p0 = __half22float2(*(const __half2*)&r0.x);
        float2 p1 = __half22float2(*(const __half2*)&r0.y);
        ax += w0 * p0.x; ay += w0 * p0.y; az += w0 * p1.x; aw += w0 * p1.y;
    }
    ax += bx; ay += by; az += bz; aw += bw;
    ax += __shfl_xor(ax, 8);
    ay += __shfl_xor(ay, 8);
    az += __shfl_xor(az, 8);
    aw += __shfl_xor(aw, 8);
    float4 fav = fown[(size_t)node * 8 + c];
    float di = dinv[node];
    float fx = fav.x - ax * di;
    float fy = fav.y - ay * di;
    float fz = fav.z - az * di;
    float fw = fav.w - aw * di;
    if (MODE != 2) {
        if (q == 0) {
            float4 t; t.x = fx; t.y = fy; t.z = fz; t.w = fw;
            fwr[(size_t)node * 8 + c] = t;
            __half2 a = __float22half2_rn(make_float2(fx * di, fy * di));
            __half2 bb = __float22half2_rn(make_float2(fz * di, fw * di));
            uint2 m;
            m.x = *(unsigned*)&a;
            m.y = *(unsigned*)&bb;
            gout[(size_t)node * 8 + c] = m;
        } else {
            float4 o;
            if (MODE == 1) {
                o.x = theta0 * fav.x + theta * fx;
                o.y = theta0 * fav.y + theta * fy;
                o.z = theta0 * fav.z + theta * fz;
                o.w = theta0 * fav.w + theta * fw;
            } else {
                o = out[(size_t)node * 8 + c];
                o.x += theta * fx; o.y += theta * fy;
                o.z += theta * fz; o.w += theta * fw;
            }
            out[(size_t)node * 8 + c] = o;
        }
    } else {
        if (q == 1) {
            float4 o = out[(size_t)node * 8 + c];
            o.x += theta * fx; o.y += theta * fy;
            o.z += theta * fz; o.w += theta * fw;
            out[(size_t)node * 8 + c] = o;
        }
    }
}

// ---------------- fallback: atomic scatter path ----------------

__global__ void fb_deg_kernel(const int* __restrict__ dst, const float* __restrict__ mask,
                              float* __restrict__ deg, int E) {
    int e = blockIdx.x * blockDim.x + threadIdx.x;
    if (e < E) atomicAdd(&deg[dst[e]], mask[e]);
}

__global__ void fb_dinv_kernel(float* __restrict__ deg, int N) {
    int i = blockIdx.x * blockDim.x + threadIdx.x;
    if (i < N) {
        float d = deg[i];
        d = d > 1.0f ? d : 1.0f;
        deg[i] = 1.0f / sqrtf(d);
    }
}

__global__ void fb_init_kernel(const float4* __restrict__ feat, float4* __restrict__ fbuf,
                               float4* __restrict__ out, int n4) {
    int i = blockIdx.x * blockDim.x + threadIdx.x;
    if (i < n4) {
        float4 f = feat[i];
        fbuf[i] = f;
        float4 o;
        o.x = 0.2f * f.x; o.y = 0.2f * f.y; o.z = 0.2f * f.z; o.w = 0.2f * f.w;
        out[i] = o;
    }
}

__global__ void fb_scatter_kernel(const float4* __restrict__ fbuf, const float* __restrict__ dinv,
                                  const int* __restrict__ src, const int* __restrict__ dst,
                                  const float* __restrict__ mask, float* __restrict__ agg, int E) {
    int t = blockIdx.x * blockDim.x + threadIdx.x;
    int e = t >> 3;
    if (e >= E) return;
    int c4 = t & 7;
    int s = src[e];
    int d = dst[e];
    float w = mask[e] * dinv[s];
    float4 f = fbuf[s * 8 + c4];
    float* ap = agg + (size_t)d * FDIM + c4 * 4;
    atomicAdd(ap + 0, f.x * w);
    atomicAdd(ap + 1, f.y * w);
    atomicAdd(ap + 2, f.z * w);
    atomicAdd(ap + 3, f.w * w);
}

__global__ void fb_update_kernel(float4* __restrict__ fbuf, float4* __restrict__ agg,
                                 const float* __restrict__ dinv, float4* __restrict__ out,
                                 float theta, int n4) {
    int t = blockIdx.x * blockDim.x + threadIdx.x;
    if (t >= n4) return;
    int node = t >> 3;
    float di = dinv[node];
    float4 a = agg[t];
    float4 z; z.x = 0.f; z.y = 0.f; z.z = 0.f; z.w = 0.f;
    agg[t] = z;
    float4 f = fbuf[t];
    f.x -= a.x * di; f.y -= a.y * di; f.z -= a.z * di; f.w -= a.w * di;
    fbuf[t] = f;
    float4 o = out[t];
    o.x += theta * f.x; o.y += theta * f.y; o.z += theta * f.z; o.w += theta * f.w;
    out[t] = o;
}

// ---------------- launch ----------------

static inline size_t align_up(size_t x) { return (x + 63) & ~(size_t)63; }  // 64-elem align

extern "C" void kernel_launch(void* const* d_in, const int* in_sizes, int n_in,
                              void* d_out, int out_size, void* d_ws, size_t ws_size,
                              hipStream_t stream) {
    const float* feat = (const float*)d_in[0];
    const int* src = (const int*)d_in[1];
    const int* dst = (const int*)d_in[2];
    const float* mask = (const float*)d_in[3];
    float* out = (float*)d_out;

    const int N = in_sizes[0] / FDIM;
    const int E = in_sizes[1];
    const float thetas[5] = {0.2f, -0.4f, 0.3f, -0.15f, 0.05f};
    const int B = 256;

    const int nbkt = (N + BKT_NODES - 1) / BKT_NODES;
    const int NBLKp = (E + S_FIX - 1) / S_FIX;

    // ws layout (4B elements, 64-elem aligned) — ALL PERSISTENT.
    size_t o_dinv = 0;                                            // N
    size_t o_rp    = align_up(o_dinv + N);                        // N+1
    size_t o_esI   = align_up(o_rp + N + 1);                      // E
    size_t o_m0    = align_up(o_esI + (size_t)E);                 // 16N
    size_t o_m1    = align_up(o_m0 + (size_t)N * 16);             // 16N
    size_t o_esp   = align_up(o_m1 + (size_t)N * 16);             // 2E
    size_t o_lofsT = align_up(o_esp + 2 * (size_t)E);             // (nbkt+1)*NBLKp
    size_t o_R     = align_up(o_lofsT + (size_t)(nbkt + 1) * NBLKp);  // nbkt+1
    size_t o_f     = align_up(o_R + nbkt + 1);                    // 32N
    size_t need = (o_f + (size_t)N * FDIM) * 4;

    float* wsf = (float*)d_ws;
    int* wsi = (int*)d_ws;

    int nbE = (E + B - 1) / B;
    int nbN = (N + B - 1) / B;

    if (ws_size >= need && N <= (1 << 17) && nbkt <= MAXBKT && NBLKp <= MAXNBLK) {
        float* dinv = wsf + o_dinv;
        int* row_ptr = wsi + o_rp;
        int* esI = wsi + o_esI;
        uint2* m0 = (uint2*)(wsi + o_m0);
        uint2* m1 = (uint2*)(wsi + o_m1);
        int2* esp = (int2*)(wsi + o_esp);
        int* lofsT = wsi + o_lofsT;
        int* R = wsi + o_R;
        float4* f = (float4*)(wsf + o_f);

        p3_kernel<<<NBLKp, 512, 0, stream>>>(src, dst, mask, lofsT, esp, NBLKp, nbkt, E);
        scanR_kernel<<<nbkt + 1, 256, 0, stream>>>(lofsT, R, NBLKp);
        p4_kernel<<<nbkt, 512, 0, stream>>>(esp, lofsT, R, esI, row_ptr, dinv,
                                            (const float4*)feat, m0, NBLKp, nbkt, N, E);

        int aggWaves = (N + 3) / 4;
        int agg_blocks = (aggWaves * 64 + B - 1) / B;
        aggregate_kernel<1><<<agg_blocks, B, 0, stream>>>((const float4*)feat, f, m0, m1,
                                                          (float4*)out, row_ptr, esI, dinv,
                                                          thetas[1], thetas[0], N);
        aggregate_kernel<0><<<agg_blocks, B, 0, stream>>>(f, f, m1, m0, (float4*)out,
                                                          row_ptr, esI, dinv, thetas[2], 0.f, N);
        aggregate_kernel<0><<<agg_blocks, B, 0, stream>>>(f, f, m0, m1, (float4*)out,
                                                          row_ptr, esI, dinv, thetas[3], 0.f, N);
        aggregate_kernel<2><<<agg_blocks, B, 0, stream>>>(f, f, m1, m0, (float4*)out,
                                                          row_ptr, esI, dinv, thetas[4], 0.f, N);
    } else {
        // fallback: atomic-scatter path
        float* deg = wsf;                       // N
        float* agg = deg + align_up(N);         // 32N
        float* fbuf = agg + (size_t)N * FDIM;   // 32N

        hipMemsetAsync(d_ws, 0, (align_up(N) + (size_t)N * FDIM) * 4, stream);
        fb_deg_kernel<<<nbE, B, 0, stream>>>(dst, mask, deg, E);
        fb_dinv_kernel<<<nbN, B, 0, stream>>>(deg, N);

        int n4 = N * (FDIM / 4);
        fb_init_kernel<<<(n4 + B - 1) / B, B, 0, stream>>>((const float4*)feat, (float4*)fbuf,
                                                           (float4*)out, n4);
        long long sc_threads = (long long)E * 8;
        int sc_blocks = (int)((sc_threads + B - 1) / B);
        for (int k = 1; k < 5; ++k) {
            fb_scatter_kernel<<<sc_blocks, B, 0, stream>>>((const float4*)fbuf, deg, src, dst,
                                                           mask, agg, E);
            fb_update_kernel<<<(n4 + B - 1) / B, B, 0, stream>>>((float4*)fbuf, (float4*)agg,
                                                                 deg, (float4*)out, thetas[k], n4);
        }
    }
}